// Round 11
// baseline (203.163 us; speedup 1.0000x reference)
//
#include <hip/hip_runtime.h>

// (B,T,C)=(2,2048,1024), NH=16, NKV=4, HD=64, VEC=32
typedef __bf16 bf16x8 __attribute__((ext_vector_type(8)));
typedef __bf16 bf16x4 __attribute__((ext_vector_type(4)));
typedef float f32x4 __attribute__((ext_vector_type(4)));

__device__ inline float tof(float v) { return v; }
__device__ inline float tof(__bf16 v) { return (float)v; }

__device__ inline bf16x8 load8(const __bf16* p) { return *(const bf16x8*)p; }
__device__ inline bf16x8 load8(const float* p) {
    const float4 a = *(const float4*)p;
    const float4 b = *(const float4*)(p + 4);
    bf16x8 r;
    r[0] = (__bf16)a.x; r[1] = (__bf16)a.y; r[2] = (__bf16)a.z; r[3] = (__bf16)a.w;
    r[4] = (__bf16)b.x; r[5] = (__bf16)b.y; r[6] = (__bf16)b.z; r[7] = (__bf16)b.w;
    return r;
}

__device__ __forceinline__ float ldT(const void* p, size_t i, int isf32) {
    return isf32 ? ((const float*)p)[i] : tof(((const __bf16*)p)[i]);
}

// async global->LDS, 16B per lane (dest = wave-uniform base + lane*16)
__device__ __forceinline__ void cp16(__bf16* lds, const __bf16* g) {
    __builtin_amdgcn_global_load_lds((__attribute__((address_space(1))) void*)g,
                                     (__attribute__((address_space(3))) void*)lds,
                                     16, 0, 0);
}

// per-block dtype sniff: 512 samples of x as bf16; fp32 reinterpreted shows
// ~68% of threads with a wild exponent, true bf16 ~0. One barrier.
__device__ __forceinline__ int sniff_block(const void* xraw) {
    const unsigned short* xs = (const unsigned short*)xraw;
    int tid = threadIdx.x;
    int bad = 0;
#pragma unroll
    for (int k = 0; k < 2; ++k) {
        float v = __uint_as_float(((unsigned int)xs[tid * 2 + k]) << 16);
        float a = fabsf(v);
        if (!(a <= 1e4f) || (a != 0.f && a < 1e-6f)) bad = 1;
    }
    return __syncthreads_count(bad) > 32;
}

// ---------------------------------------------------------------------------
// Kernel 1: prep — transpose weights to B^T bf16 + convert Wgate.
// Grid: 641. [0,640) transpose tiles, 640 = Wg.
// ---------------------------------------------------------------------------
template <typename T>
__device__ __forceinline__ void prep_body(
    const T* __restrict__ Wq, const T* __restrict__ Wk,
    const T* __restrict__ Wv, const T* __restrict__ Wp, const T* __restrict__ Wg,
    __bf16* __restrict__ WqT, __bf16* __restrict__ WkT,
    __bf16* __restrict__ WvT, __bf16* __restrict__ WpT,
    __bf16* __restrict__ wgb, __bf16* tile)
{
    const int b = blockIdx.x, tid = threadIdx.x;
    if (b < 640) {
        int idx = b;
        const T* src; __bf16* dst; int C;
        if (idx < 256)      { src = Wq; dst = WqT; C = 1024; }
        else if (idx < 320) { src = Wk; dst = WkT; C = 256;  idx -= 256; }
        else if (idx < 384) { src = Wv; dst = WvT; C = 256;  idx -= 320; }
        else                { src = Wp; dst = WpT; C = 1024; idx -= 384; }
        const int ctiles = C >> 6;
        const int r0 = (idx / ctiles) * 64, c0 = (idx % ctiles) * 64;
#pragma unroll
        for (int i = 0; i < 2; ++i) {
            int c = tid + i * 256, ir = c >> 3, ic = (c & 7) * 8;
            *(bf16x8*)(&tile[ir * 72 + ic]) = load8(src + (size_t)(r0 + ir) * C + c0 + ic);
        }
        __syncthreads();
#pragma unroll
        for (int i = 0; i < 2; ++i) {
            int c = tid + i * 256, orr = c >> 3, okc = (c & 7) * 8;
            bf16x8 v;
#pragma unroll
            for (int j = 0; j < 8; ++j) v[j] = tile[(okc + j) * 72 + orr];
            *(bf16x8*)(dst + (size_t)(c0 + orr) * 1024 + r0 + okc) = v;
        }
    } else if (tid < 128) {
        wgb[tid] = (__bf16)tof(Wg[tid]);
    }
}

__global__ __launch_bounds__(256) void prep_kernel(
    const void* x,
    const void* Wq, const void* Wk, const void* Wv, const void* Wp, const void* Wg,
    __bf16* WqT, __bf16* WkT, __bf16* WvT, __bf16* WpT, __bf16* wgb)
{
    __shared__ __bf16 tile[64 * 72];
    const int isf32 = sniff_block(x);
    if (isf32) {
        prep_body<float>((const float*)Wq, (const float*)Wk, (const float*)Wv,
                         (const float*)Wp, (const float*)Wg,
                         WqT, WkT, WvT, WpT, wgb, tile);
    } else {
        prep_body<__bf16>((const __bf16*)Wq, (const __bf16*)Wk, (const __bf16*)Wv,
                          (const __bf16*)Wp, (const __bf16*)Wg,
                          WqT, WkT, WvT, WpT, wgb, tile);
    }
}

// ---------------------------------------------------------------------------
// Kernel 2: QKV GEMM, 128x64 tiles, BK=64, LDS double-buffered (48KB -> 3
// blocks/CU). x/ve/cos/sin read DIRECTLY (dtype-branched). Gate via MFMA at
// kk==0. q written pre-scaled by log2e/8 for attn. V transposed. Grid (32,24).
// ---------------------------------------------------------------------------
__global__ __launch_bounds__(256) void qkv_kernel(
    const void* __restrict__ xraw, const void* __restrict__ veraw,
    const void* __restrict__ cosraw, const void* __restrict__ sinraw,
    const __bf16* __restrict__ WqT, const __bf16* __restrict__ WkT,
    const __bf16* __restrict__ WvT, const __bf16* __restrict__ wgb,
    __bf16* __restrict__ qo, __bf16* __restrict__ ko, __bf16* __restrict__ vTo)
{
    const int isf32 = sniff_block(xraw);
    const __bf16* xb = (const __bf16*)xraw;
    const float*  xf = (const float*)xraw;

    const int row0 = blockIdx.x * 128;
    const int cb = blockIdx.y;
    const __bf16* BT; int col0, h, mode;
    if (cb < 16)      { BT = WqT; col0 = cb * 64;        h = cb;      mode = 0; }
    else if (cb < 20) { BT = WkT; col0 = (cb - 16) * 64; h = cb - 16; mode = 1; }
    else              { BT = WvT; col0 = (cb - 20) * 64; h = cb - 20; mode = 2; }

    __shared__ __align__(16) __bf16 As[2][128 * 64];
    __shared__ __align__(16) __bf16 Bs[2][64 * 64];

    const int tid  = threadIdx.x;
    const int w    = tid >> 6;
    const int lane = tid & 63;
    const int quad = lane >> 4;
    const int l15  = lane & 15;
    const int wr   = w * 32;

    f32x4 acc[2][4];
#pragma unroll
    for (int mi = 0; mi < 2; ++mi)
#pragma unroll
        for (int nj = 0; nj < 4; ++nj) acc[mi][nj] = (f32x4){0.f, 0.f, 0.f, 0.f};

    // gate B-fragment: Wg[k=quad*8+j][n=l15], cols >=4 zero
    bf16x8 wgB;
#pragma unroll
    for (int j = 0; j < 8; ++j) wgB[j] = (__bf16)0.f;
    if (mode == 2 && l15 < 4) {
#pragma unroll
        for (int j = 0; j < 8; ++j) wgB[j] = wgb[(quad * 8 + j) * 4 + l15];
    }
    f32x4 zacc[2];
    zacc[0] = (f32x4){0.f, 0.f, 0.f, 0.f};
    zacc[1] = (f32x4){0.f, 0.f, 0.f, 0.f};

    // A tile: 128x64 = 1024 16B-chunks (4/thread); B tile: 64x64 = 512 (2/thread)
    auto stageA_bf = [&](int buf, int kk) {
#pragma unroll
        for (int i = 0; i < 4; ++i) {
            int c = i * 256 + tid;
            cp16(&As[buf][c * 8], &xb[(size_t)(row0 + (c >> 3)) * 1024 + kk + ((c & 7) << 3)]);
        }
    };
    auto stageA_f32 = [&](int buf, int kk) {
#pragma unroll
        for (int i = 0; i < 4; ++i) {
            int c = i * 256 + tid;
            *(bf16x8*)(&As[buf][c * 8]) = load8(&xf[(size_t)(row0 + (c >> 3)) * 1024 + kk + ((c & 7) << 3)]);
        }
    };
    auto stageB = [&](int buf, int kk) {
#pragma unroll
        for (int i = 0; i < 2; ++i) {
            int c = i * 256 + tid;
            cp16(&Bs[buf][c * 8], &BT[(size_t)(col0 + (c >> 3)) * 1024 + kk + ((c & 7) << 3)]);
        }
    };

    if (isf32) stageA_f32(0, 0); else stageA_bf(0, 0);
    stageB(0, 0);
    __syncthreads();

    for (int kk = 0; kk < 1024; kk += 64) {
        const int cur = (kk >> 6) & 1;
        const bool more = (kk + 64 < 1024);
        if (more) {
            if (isf32) stageA_f32(cur ^ 1, kk + 64); else stageA_bf(cur ^ 1, kk + 64);
            stageB(cur ^ 1, kk + 64);
        }

        bf16x8 a[2][2], bfr[4][2];
#pragma unroll
        for (int mi = 0; mi < 2; ++mi)
#pragma unroll
            for (int kh = 0; kh < 2; ++kh)
                a[mi][kh] = *(const bf16x8*)(&As[cur][(wr + mi * 16 + l15) * 64 + kh * 32 + quad * 8]);
#pragma unroll
        for (int nj = 0; nj < 4; ++nj)
#pragma unroll
            for (int kh = 0; kh < 2; ++kh)
                bfr[nj][kh] = *(const bf16x8*)(&Bs[cur][(nj * 16 + l15) * 64 + kh * 32 + quad * 8]);

        if (mode == 2 && kk == 0) {        // gate z = x[:,0:32] @ Wg
            zacc[0] = __builtin_amdgcn_mfma_f32_16x16x32_bf16(a[0][0], wgB, zacc[0], 0, 0, 0);
            zacc[1] = __builtin_amdgcn_mfma_f32_16x16x32_bf16(a[1][0], wgB, zacc[1], 0, 0, 0);
        }
#pragma unroll
        for (int kh = 0; kh < 2; ++kh)
#pragma unroll
            for (int mi = 0; mi < 2; ++mi)
#pragma unroll
                for (int nj = 0; nj < 4; ++nj)
                    acc[mi][nj] = __builtin_amdgcn_mfma_f32_16x16x32_bf16(a[mi][kh], bfr[nj][kh], acc[mi][nj], 0, 0, 0);
        __syncthreads();
    }

    if (mode < 2) {
        __bf16* dst = (mode == 0) ? qo : ko;
        const int nh = (mode == 0) ? 16 : 4;
        const float post = (mode == 0) ? 0.18033688f : 1.0f;   // fold softmax scale into q
#pragma unroll
        for (int mi = 0; mi < 2; ++mi) {
#pragma unroll
            for (int r = 0; r < 4; ++r) {
                int row = row0 + wr + mi * 16 + quad * 4 + r;
                int b = row >> 11, t = row & 2047;
                float c0 = ldT(cosraw, t * 32 + l15, isf32);
                float c1 = ldT(cosraw, t * 32 + 16 + l15, isf32);
                float s0 = ldT(sinraw, t * 32 + l15, isf32);
                float s1 = ldT(sinraw, t * 32 + 16 + l15, isf32);
                float v0 =  c0 * acc[mi][0][r] + s0 * acc[mi][2][r];
                float v1 =  c1 * acc[mi][1][r] + s1 * acc[mi][3][r];
                float v2 = -s0 * acc[mi][0][r] + c0 * acc[mi][2][r];
                float v3 = -s1 * acc[mi][1][r] + c1 * acc[mi][3][r];
                float ss = v0 * v0 + v1 * v1 + v2 * v2 + v3 * v3;
                ss += __shfl_xor(ss, 1); ss += __shfl_xor(ss, 2);
                ss += __shfl_xor(ss, 4); ss += __shfl_xor(ss, 8);
                float sc = rsqrtf(ss * (1.f / 64.f) + 1.1920929e-7f) * post;
                size_t base = (((size_t)b * nh + h) * 2048 + t) * 64;
                dst[base + 0 * 16 + l15] = (__bf16)(v0 * sc);
                dst[base + 1 * 16 + l15] = (__bf16)(v1 * sc);
                dst[base + 2 * 16 + l15] = (__bf16)(v2 * sc);
                dst[base + 3 * 16 + l15] = (__bf16)(v3 * sc);
            }
        }
    } else {
        // vT[(b*4+h)*64 + d][t], packed 4 consecutive t per store
#pragma unroll
        for (int mi = 0; mi < 2; ++mi) {
            int rowb = row0 + wr + mi * 16 + quad * 4;
            int b = rowb >> 11, t0 = rowb & 2047;
            float gg[4];
#pragma unroll
            for (int r = 0; r < 4; ++r) {
                float zv = __shfl(zacc[mi][r], quad * 16 + h);
                gg[r] = 2.f / (1.f + __expf(-zv));
            }
#pragma unroll
            for (int nj = 0; nj < 4; ++nj) {
                int d = nj * 16 + l15;
                bf16x4 pack;
#pragma unroll
                for (int r = 0; r < 4; ++r) {
                    int row = rowb + r;
                    float vev = ldT(veraw, (size_t)row * 256 + h * 64 + d, isf32);
                    pack[r] = (__bf16)(acc[mi][nj][r] + gg[r] * vev);
                }
                size_t a = (((size_t)b * 4 + h) * 64 + d) * 2048 + t0;
                *(bf16x4*)(&vTo[a]) = pack;
            }
        }
    }
}

// ---------------------------------------------------------------------------
// Kernel 3: sliding-window causal GQA flash attention (round-7 structure).
// q pre-scaled in qkv -> p = exp2(s), no fma/constant. Grid (16,16,2).
// ---------------------------------------------------------------------------
__global__ __launch_bounds__(256) void attn_kernel(
    const __bf16* __restrict__ qg, const __bf16* __restrict__ kg,
    const __bf16* __restrict__ vTg, __bf16* __restrict__ yo,
    const int* __restrict__ winp)
{
    const int q0 = blockIdx.x * 128;
    const int hh = blockIdx.y, b = blockIdx.z;
    const int kvh = hh >> 2;
    const int W = winp[0];

    const int tid  = threadIdx.x;
    const int w    = tid >> 6;
    const int lane = tid & 63;
    const int quad = lane >> 4;
    const int l15  = lane & 15;

    __shared__ __align__(16) __bf16 Ks[2][64 * 64];   // [t][d], XOR-swizzled
    __shared__ __align__(16) __bf16 Vt[2][64 * 64];   // [d][t], XOR-swizzled
    __shared__ __align__(16) __bf16 Ps[4][32 * 72];   // per-wave P

    bf16x8 qf[2][2];
#pragma unroll
    for (int i = 0; i < 2; ++i) {
        size_t qb = (((size_t)b * 16 + hh) * 2048 + q0 + w * 32 + i * 16 + l15) * 64;
        qf[i][0] = *(const bf16x8*)(&qg[qb + quad * 8]);
        qf[i][1] = *(const bf16x8*)(&qg[qb + 32 + quad * 8]);
    }

    f32x4 oacc[2][4];
    float lsum[2][4];
#pragma unroll
    for (int i = 0; i < 2; ++i)
#pragma unroll
        for (int n = 0; n < 4; ++n) {
            oacc[i][n] = (f32x4){0.f, 0.f, 0.f, 0.f};
            lsum[i][n] = 0.f;
        }

    const int lo = q0 - W;
    const int kt_lo = lo > 0 ? (lo >> 6) : 0;
    const int kt_hi = (q0 + 127) >> 6;
    const size_t kvbase = ((size_t)b * 4 + kvh) * 2048 * 64;

    auto stage = [&](int buf, int k0) {
#pragma unroll
        for (int i = 0; i < 2; ++i) {
            int c = i * 256 + tid;
            int rr = c >> 3;
            int jj = (c & 7) ^ (rr & 7);
            cp16(&Ks[buf][c * 8], &kg[kvbase + (size_t)(k0 + rr) * 64 + jj * 8]);
            cp16(&Vt[buf][c * 8], &vTg[kvbase + (size_t)rr * 2048 + k0 + jj * 8]);
        }
    };

    stage(0, kt_lo * 64);
    __syncthreads();

    int cur = 0;
    for (int kt = kt_lo; kt <= kt_hi; ++kt) {
        const int k0 = kt * 64;
        const bool need_mask = (k0 + 63 > q0) || (q0 + 127 - k0 > W);
        if (kt < kt_hi) stage(cur ^ 1, k0 + 64);    // async prefetch

        // QK^T
        f32x4 sacc[2][4];
#pragma unroll
        for (int i = 0; i < 2; ++i)
#pragma unroll
            for (int n = 0; n < 4; ++n) sacc[i][n] = (f32x4){0.f, 0.f, 0.f, 0.f};
        const __bf16* Kc = &Ks[cur][0];
#pragma unroll
        for (int n = 0; n < 4; ++n) {
            int m = n * 16 + l15;
            bf16x8 b0 = *(const bf16x8*)(&Kc[m * 64 + (quad ^ (m & 7)) * 8]);
            bf16x8 b1 = *(const bf16x8*)(&Kc[m * 64 + ((4 + quad) ^ (m & 7)) * 8]);
#pragma unroll
            for (int i = 0; i < 2; ++i) {
                sacc[i][n] = __builtin_amdgcn_mfma_f32_16x16x32_bf16(qf[i][0], b0, sacc[i][n], 0, 0, 0);
                sacc[i][n] = __builtin_amdgcn_mfma_f32_16x16x32_bf16(qf[i][1], b1, sacc[i][n], 0, 0, 0);
            }
        }

        // softmax: q pre-scaled -> p = exp2(s); common factor cancels in o/l
#pragma unroll
        for (int i = 0; i < 2; ++i) {
#pragma unroll
            for (int r = 0; r < 4; ++r) {
                const int row_g = q0 + w * 32 + i * 16 + quad * 4 + r;
#pragma unroll
                for (int n = 0; n < 4; ++n) {
                    float p = exp2f(sacc[i][n][r]);
                    if (need_mask) {
                        int col_g = k0 + n * 16 + l15;
                        bool ok = (col_g <= row_g) && (row_g - col_g <= W);
                        p = ok ? p : 0.f;
                    }
                    lsum[i][r] += p;
                    Ps[w][(i * 16 + quad * 4 + r) * 72 + n * 16 + l15] = (__bf16)p;
                }
            }
        }
        asm volatile("s_waitcnt lgkmcnt(0)" ::: "memory");   // wave-local Ps ordering

        // PV
        const __bf16* Vc = &Vt[cur][0];
#pragma unroll
        for (int ks = 0; ks < 2; ++ks) {
            bf16x8 pfr0 = *(const bf16x8*)(&Ps[w][l15 * 72 + ks * 32 + quad * 8]);
            bf16x8 pfr1 = *(const bf16x8*)(&Ps[w][(16 + l15) * 72 + ks * 32 + quad * 8]);
#pragma unroll
            for (int n = 0; n < 4; ++n) {
                int m = n * 16 + l15;
                bf16x8 bv = *(const bf16x8*)(&Vc[m * 64 + ((ks * 4 + quad) ^ (m & 7)) * 8]);
                oacc[0][n] = __builtin_amdgcn_mfma_f32_16x16x32_bf16(pfr0, bv, oacc[0][n], 0, 0, 0);
                oacc[1][n] = __builtin_amdgcn_mfma_f32_16x16x32_bf16(pfr1, bv, oacc[1][n], 0, 0, 0);
            }
        }

        __syncthreads();   // drains prefetch cp16 + protects buffers
        cur ^= 1;
    }

#pragma unroll
    for (int i = 0; i < 2; ++i) {
#pragma unroll
        for (int r = 0; r < 4; ++r) {
            float l = lsum[i][r];
            l += __shfl_xor(l, 1); l += __shfl_xor(l, 2);
            l += __shfl_xor(l, 4); l += __shfl_xor(l, 8);
            float inv = 1.f / l;
            int t = q0 + w * 32 + i * 16 + quad * 4 + r;
            size_t base = ((size_t)(b * 2048 + t)) * 1024 + hh * 64;
#pragma unroll
            for (int n = 0; n < 4; ++n)
                yo[base + n * 16 + l15] = (__bf16)(oacc[i][n][r] * inv);
        }
    }
}

// ---------------------------------------------------------------------------
// Kernel 4: output projection, 128x64 tiles, BK=64 double-buffered.
// Output dtype via self-sniff of x. Grid: (32, 16).
// ---------------------------------------------------------------------------
__global__ __launch_bounds__(256) void proj_kernel(
    const __bf16* __restrict__ y, const __bf16* __restrict__ WpT,
    void* __restrict__ outp, const void* __restrict__ xraw)
{
    const int isf32 = sniff_block(xraw);
    const int row0 = blockIdx.x * 128;
    const int col0 = blockIdx.y * 64;
    __shared__ __align__(16) __bf16 As[2][128 * 64];
    __shared__ __align__(16) __bf16 Bs[2][64 * 64];

    const int tid  = threadIdx.x;
    const int w    = tid >> 6;
    const int lane = tid & 63;
    const int quad = lane >> 4;
    const int l15  = lane & 15;
    const int wr   = w * 32;

    f32x4 acc[2][4];
#pragma unroll
    for (int mi = 0; mi < 2; ++mi)
#pragma unroll
        for (int nj = 0; nj < 4; ++nj) acc[mi][nj] = (f32x4){0.f, 0.f, 0.f, 0.f};

    auto stage = [&](int buf, int kk) {
#pragma unroll
        for (int i = 0; i < 4; ++i) {
            int c = i * 256 + tid;
            cp16(&As[buf][c * 8], &y[(size_t)(row0 + (c >> 3)) * 1024 + kk + ((c & 7) << 3)]);
        }
#pragma unroll
        for (int i = 0; i < 2; ++i) {
            int c = i * 256 + tid;
            cp16(&Bs[buf][c * 8], &WpT[(size_t)(col0 + (c >> 3)) * 1024 + kk + ((c & 7) << 3)]);
        }
    };

    stage(0, 0);
    __syncthreads();

    for (int kk = 0; kk < 1024; kk += 64) {
        const int cur = (kk >> 6) & 1;
        if (kk + 64 < 1024) stage(cur ^ 1, kk + 64);

        bf16x8 a[2][2], bfr[4][2];
#pragma unroll
        for (int mi = 0; mi < 2; ++mi)
#pragma unroll
            for (int kh = 0; kh < 2; ++kh)
                a[mi][kh] = *(const bf16x8*)(&As[cur][(wr + mi * 16 + l15) * 64 + kh * 32 + quad * 8]);
#pragma unroll
        for (int nj = 0; nj < 4; ++nj)
#pragma unroll
            for (int kh = 0; kh < 2; ++kh)
                bfr[nj][kh] = *(const bf16x8*)(&Bs[cur][(nj * 16 + l15) * 64 + kh * 32 + quad * 8]);
#pragma unroll
        for (int kh = 0; kh < 2; ++kh)
#pragma unroll
            for (int mi = 0; mi < 2; ++mi)
#pragma unroll
                for (int nj = 0; nj < 4; ++nj)
                    acc[mi][nj] = __builtin_amdgcn_mfma_f32_16x16x32_bf16(a[mi][kh], bfr[nj][kh], acc[mi][nj], 0, 0, 0);
        __syncthreads();
    }

#pragma unroll
    for (int mi = 0; mi < 2; ++mi)
#pragma unroll
        for (int r = 0; r < 4; ++r) {
            int row = row0 + wr + mi * 16 + quad * 4 + r;
            if (isf32) {
                float* out = (float*)outp;
#pragma unroll
                for (int nj = 0; nj < 4; ++nj)
                    out[(size_t)row * 1024 + col0 + nj * 16 + l15] = acc[mi][nj][r];
            } else {
                __bf16* out = (__bf16*)outp;
#pragma unroll
                for (int nj = 0; nj < 4; ++nj)
                    out[(size_t)row * 1024 + col0 + nj * 16 + l15] = (__bf16)acc[mi][nj][r];
            }
        }
}

extern "C" void kernel_launch(void* const* d_in, const int* in_sizes, int n_in,
                              void* d_out, int out_size, void* d_ws, size_t ws_size,
                              hipStream_t stream) {
    const int* win = (const int*)d_in[9];

    char* p = (char*)d_ws;
    __bf16* q_ws = (__bf16*)p;                 p += (size_t)4194304 * 2;
    __bf16* k_ws = (__bf16*)p;                 p += (size_t)1048576 * 2;
    __bf16* vT_ws= (__bf16*)p;                 p += (size_t)1048576 * 2;
    __bf16* y_ws = (__bf16*)p;                 p += (size_t)4194304 * 2;
    __bf16* WqT  = (__bf16*)p;                 p += (size_t)1048576 * 2;
    __bf16* WkT  = (__bf16*)p;                 p += (size_t)262144 * 2;
    __bf16* WvT  = (__bf16*)p;                 p += (size_t)262144 * 2;
    __bf16* WpT  = (__bf16*)p;                 p += (size_t)1048576 * 2;
    __bf16* wgb  = (__bf16*)p;                 p += 256;

    prep_kernel<<<641, 256, 0, stream>>>(
        d_in[0], d_in[4], d_in[5], d_in[6], d_in[7], d_in[8],
        WqT, WkT, WvT, WpT, wgb);

    qkv_kernel<<<dim3(32, 24), 256, 0, stream>>>(
        d_in[0], d_in[1], d_in[2], d_in[3],
        WqT, WkT, WvT, wgb, q_ws, k_ws, vT_ws);

    attn_kernel<<<dim3(16, 16, 2), 256, 0, stream>>>(q_ws, k_ws, vT_ws, y_ws, win);

    proj_kernel<<<dim3(32, 16), 256, 0, stream>>>(y_ws, WpT, d_out, d_in[0]);
}

// Round 12
// 193.479 us; speedup vs baseline: 1.0501x; 1.0501x over previous
//
#include <hip/hip_runtime.h>

// (B,T,C)=(2,2048,1024), NH=16, NKV=4, HD=64, VEC=32
typedef __bf16 bf16x8 __attribute__((ext_vector_type(8)));
typedef __bf16 bf16x4 __attribute__((ext_vector_type(4)));
typedef float f32x4 __attribute__((ext_vector_type(4)));

__device__ inline float tof(float v) { return v; }
__device__ inline float tof(__bf16 v) { return (float)v; }

__device__ inline bf16x8 load8(const __bf16* p) { return *(const bf16x8*)p; }
__device__ inline bf16x8 load8(const float* p) {
    const float4 a = *(const float4*)p;
    const float4 b = *(const float4*)(p + 4);
    bf16x8 r;
    r[0] = (__bf16)a.x; r[1] = (__bf16)a.y; r[2] = (__bf16)a.z; r[3] = (__bf16)a.w;
    r[4] = (__bf16)b.x; r[5] = (__bf16)b.y; r[6] = (__bf16)b.z; r[7] = (__bf16)b.w;
    return r;
}

__device__ __forceinline__ float ldT(const void* p, size_t i, int isf32) {
    return isf32 ? ((const float*)p)[i] : tof(((const __bf16*)p)[i]);
}

// async global->LDS, 16B per lane (dest = wave-uniform base + lane*16)
__device__ __forceinline__ void cp16(__bf16* lds, const __bf16* g) {
    __builtin_amdgcn_global_load_lds((__attribute__((address_space(1))) void*)g,
                                     (__attribute__((address_space(3))) void*)lds,
                                     16, 0, 0);
}

// per-block dtype sniff (one barrier): fp32-as-bf16 shows wild exponents
__device__ __forceinline__ int sniff_block(const void* xraw) {
    const unsigned short* xs = (const unsigned short*)xraw;
    int tid = threadIdx.x;
    int bad = 0;
#pragma unroll
    for (int k = 0; k < 2; ++k) {
        float v = __uint_as_float(((unsigned int)xs[tid * 2 + k]) << 16);
        float a = fabsf(v);
        if (!(a <= 1e4f) || (a != 0.f && a < 1e-6f)) bad = 1;
    }
    return __syncthreads_count(bad) > 32;
}

// ---------------------------------------------------------------------------
// Kernel 1: prep — convert x to bf16 (so qkv can cp16-stage it), transpose
// weights to B^T bf16, convert Wgate.
// Grid: 2689. [0,2048) x-convert, [2048,2688) transpose, 2688 = Wg.
// ---------------------------------------------------------------------------
template <typename T>
__device__ __forceinline__ void prep_body(
    const T* __restrict__ x,
    const T* __restrict__ Wq, const T* __restrict__ Wk,
    const T* __restrict__ Wv, const T* __restrict__ Wp, const T* __restrict__ Wg,
    __bf16* __restrict__ xb,
    __bf16* __restrict__ WqT, __bf16* __restrict__ WkT,
    __bf16* __restrict__ WvT, __bf16* __restrict__ WpT,
    __bf16* __restrict__ wgb, __bf16* tile)
{
    const int b = blockIdx.x, tid = threadIdx.x;
    if (b < 2048) {
        int g = b * 256 + tid;     // 8 elems each, 4.19M total
        *(bf16x8*)(xb + (size_t)g * 8) = load8(x + (size_t)g * 8);
    } else if (b < 2688) {         // 64x64 tile transpose
        int idx = b - 2048;
        const T* src; __bf16* dst; int C;
        if (idx < 256)      { src = Wq; dst = WqT; C = 1024; }
        else if (idx < 320) { src = Wk; dst = WkT; C = 256;  idx -= 256; }
        else if (idx < 384) { src = Wv; dst = WvT; C = 256;  idx -= 320; }
        else                { src = Wp; dst = WpT; C = 1024; idx -= 384; }
        const int ctiles = C >> 6;
        const int r0 = (idx / ctiles) * 64, c0 = (idx % ctiles) * 64;
#pragma unroll
        for (int i = 0; i < 2; ++i) {
            int c = tid + i * 256, ir = c >> 3, ic = (c & 7) * 8;
            *(bf16x8*)(&tile[ir * 72 + ic]) = load8(src + (size_t)(r0 + ir) * C + c0 + ic);
        }
        __syncthreads();
#pragma unroll
        for (int i = 0; i < 2; ++i) {
            int c = tid + i * 256, orr = c >> 3, okc = (c & 7) * 8;
            bf16x8 v;
#pragma unroll
            for (int j = 0; j < 8; ++j) v[j] = tile[(okc + j) * 72 + orr];
            *(bf16x8*)(dst + (size_t)(c0 + orr) * 1024 + r0 + okc) = v;
        }
    } else if (tid < 128) {
        wgb[tid] = (__bf16)tof(Wg[tid]);
    }
}

__global__ __launch_bounds__(256) void prep_kernel(
    const void* x,
    const void* Wq, const void* Wk, const void* Wv, const void* Wp, const void* Wg,
    __bf16* xb,
    __bf16* WqT, __bf16* WkT, __bf16* WvT, __bf16* WpT, __bf16* wgb)
{
    __shared__ __bf16 tile[64 * 72];
    const int isf32 = sniff_block(x);
    if (isf32) {
        prep_body<float>((const float*)x, (const float*)Wq, (const float*)Wk,
                         (const float*)Wv, (const float*)Wp, (const float*)Wg,
                         xb, WqT, WkT, WvT, WpT, wgb, tile);
    } else {
        prep_body<__bf16>((const __bf16*)x, (const __bf16*)Wq, (const __bf16*)Wk,
                          (const __bf16*)Wv, (const __bf16*)Wp, (const __bf16*)Wg,
                          xb, WqT, WkT, WvT, WpT, wgb, tile);
    }
}

// ---------------------------------------------------------------------------
// Kernel 2: QKV GEMM, 128x64 tiles, BK=64, cp16 double-buffered staging
// (48KB -> 3 blocks/CU). Gate via MFMA at kk==0. q pre-scaled by log2e/8.
// V written transposed vT[b][kvh][d][t]. Grid (32,24).
// ---------------------------------------------------------------------------
__global__ __launch_bounds__(256) void qkv_kernel(
    const __bf16* __restrict__ xb,
    const void* __restrict__ xraw, const void* __restrict__ veraw,
    const void* __restrict__ cosraw, const void* __restrict__ sinraw,
    const __bf16* __restrict__ WqT, const __bf16* __restrict__ WkT,
    const __bf16* __restrict__ WvT, const __bf16* __restrict__ wgb,
    __bf16* __restrict__ qo, __bf16* __restrict__ ko, __bf16* __restrict__ vTo)
{
    const int isf32 = sniff_block(xraw);   // for epilogue ve/cos/sin reads

    const int row0 = blockIdx.x * 128;
    const int cb = blockIdx.y;
    const __bf16* BT; int col0, h, mode;
    if (cb < 16)      { BT = WqT; col0 = cb * 64;        h = cb;      mode = 0; }
    else if (cb < 20) { BT = WkT; col0 = (cb - 16) * 64; h = cb - 16; mode = 1; }
    else              { BT = WvT; col0 = (cb - 20) * 64; h = cb - 20; mode = 2; }

    __shared__ __align__(16) __bf16 As[2][128 * 64];
    __shared__ __align__(16) __bf16 Bs[2][64 * 64];

    const int tid  = threadIdx.x;
    const int w    = tid >> 6;
    const int lane = tid & 63;
    const int quad = lane >> 4;
    const int l15  = lane & 15;
    const int wr   = w * 32;

    f32x4 acc[2][4];
#pragma unroll
    for (int mi = 0; mi < 2; ++mi)
#pragma unroll
        for (int nj = 0; nj < 4; ++nj) acc[mi][nj] = (f32x4){0.f, 0.f, 0.f, 0.f};

    // gate B-fragment: Wg[k=quad*8+j][n=l15], cols >=4 zero
    bf16x8 wgB;
#pragma unroll
    for (int j = 0; j < 8; ++j) wgB[j] = (__bf16)0.f;
    if (mode == 2 && l15 < 4) {
#pragma unroll
        for (int j = 0; j < 8; ++j) wgB[j] = wgb[(quad * 8 + j) * 4 + l15];
    }
    f32x4 zacc[2];
    zacc[0] = (f32x4){0.f, 0.f, 0.f, 0.f};
    zacc[1] = (f32x4){0.f, 0.f, 0.f, 0.f};

    auto stage = [&](int buf, int kk) {
#pragma unroll
        for (int i = 0; i < 4; ++i) {      // A: 128x64 = 1024 chunks
            int c = i * 256 + tid;
            cp16(&As[buf][c * 8], &xb[(size_t)(row0 + (c >> 3)) * 1024 + kk + ((c & 7) << 3)]);
        }
#pragma unroll
        for (int i = 0; i < 2; ++i) {      // B: 64x64 = 512 chunks
            int c = i * 256 + tid;
            cp16(&Bs[buf][c * 8], &BT[(size_t)(col0 + (c >> 3)) * 1024 + kk + ((c & 7) << 3)]);
        }
    };

    stage(0, 0);
    __syncthreads();

    for (int kk = 0; kk < 1024; kk += 64) {
        const int cur = (kk >> 6) & 1;
        if (kk + 64 < 1024) stage(cur ^ 1, kk + 64);   // async prefetch

        bf16x8 a[2][2], bfr[4][2];
#pragma unroll
        for (int mi = 0; mi < 2; ++mi)
#pragma unroll
            for (int kh = 0; kh < 2; ++kh)
                a[mi][kh] = *(const bf16x8*)(&As[cur][(wr + mi * 16 + l15) * 64 + kh * 32 + quad * 8]);
#pragma unroll
        for (int nj = 0; nj < 4; ++nj)
#pragma unroll
            for (int kh = 0; kh < 2; ++kh)
                bfr[nj][kh] = *(const bf16x8*)(&Bs[cur][(nj * 16 + l15) * 64 + kh * 32 + quad * 8]);

        if (mode == 2 && kk == 0) {        // gate z = x[:,0:32] @ Wg
            zacc[0] = __builtin_amdgcn_mfma_f32_16x16x32_bf16(a[0][0], wgB, zacc[0], 0, 0, 0);
            zacc[1] = __builtin_amdgcn_mfma_f32_16x16x32_bf16(a[1][0], wgB, zacc[1], 0, 0, 0);
        }
#pragma unroll
        for (int kh = 0; kh < 2; ++kh)
#pragma unroll
            for (int mi = 0; mi < 2; ++mi)
#pragma unroll
                for (int nj = 0; nj < 4; ++nj)
                    acc[mi][nj] = __builtin_amdgcn_mfma_f32_16x16x32_bf16(a[mi][kh], bfr[nj][kh], acc[mi][nj], 0, 0, 0);
        __syncthreads();
    }

    if (mode < 2) {
        __bf16* dst = (mode == 0) ? qo : ko;
        const int nh = (mode == 0) ? 16 : 4;
        const float post = (mode == 0) ? 0.18033688f : 1.0f;   // fold softmax scale into q
#pragma unroll
        for (int mi = 0; mi < 2; ++mi) {
#pragma unroll
            for (int r = 0; r < 4; ++r) {
                int row = row0 + wr + mi * 16 + quad * 4 + r;
                int b = row >> 11, t = row & 2047;
                float c0 = ldT(cosraw, t * 32 + l15, isf32);
                float c1 = ldT(cosraw, t * 32 + 16 + l15, isf32);
                float s0 = ldT(sinraw, t * 32 + l15, isf32);
                float s1 = ldT(sinraw, t * 32 + 16 + l15, isf32);
                float v0 =  c0 * acc[mi][0][r] + s0 * acc[mi][2][r];
                float v1 =  c1 * acc[mi][1][r] + s1 * acc[mi][3][r];
                float v2 = -s0 * acc[mi][0][r] + c0 * acc[mi][2][r];
                float v3 = -s1 * acc[mi][1][r] + c1 * acc[mi][3][r];
                float ss = v0 * v0 + v1 * v1 + v2 * v2 + v3 * v3;
                ss += __shfl_xor(ss, 1); ss += __shfl_xor(ss, 2);
                ss += __shfl_xor(ss, 4); ss += __shfl_xor(ss, 8);
                float sc = rsqrtf(ss * (1.f / 64.f) + 1.1920929e-7f) * post;
                size_t base = (((size_t)b * nh + h) * 2048 + t) * 64;
                dst[base + 0 * 16 + l15] = (__bf16)(v0 * sc);
                dst[base + 1 * 16 + l15] = (__bf16)(v1 * sc);
                dst[base + 2 * 16 + l15] = (__bf16)(v2 * sc);
                dst[base + 3 * 16 + l15] = (__bf16)(v3 * sc);
            }
        }
    } else {
        // vT[(b*4+h)*64 + d][t], packed 4 consecutive t per store
#pragma unroll
        for (int mi = 0; mi < 2; ++mi) {
            int rowb = row0 + wr + mi * 16 + quad * 4;
            int b = rowb >> 11, t0 = rowb & 2047;
            float gg[4];
#pragma unroll
            for (int r = 0; r < 4; ++r) {
                float zv = __shfl(zacc[mi][r], quad * 16 + h);
                gg[r] = 2.f / (1.f + __expf(-zv));
            }
#pragma unroll
            for (int nj = 0; nj < 4; ++nj) {
                int d = nj * 16 + l15;
                bf16x4 pack;
#pragma unroll
                for (int r = 0; r < 4; ++r) {
                    int row = rowb + r;
                    float vev = ldT(veraw, (size_t)row * 256 + h * 64 + d, isf32);
                    pack[r] = (__bf16)(acc[mi][nj][r] + gg[r] * vev);
                }
                size_t a = (((size_t)b * 4 + h) * 64 + d) * 2048 + t0;
                *(bf16x4*)(&vTo[a]) = pack;
            }
        }
    }
}

// ---------------------------------------------------------------------------
// Kernel 3: sliding-window causal GQA flash attention (round-7 structure).
// qb reflected by batch so co-scheduled blocks pair heavy+light work.
// p = exp2(s) (q pre-scaled). Grid (16,16,2).
// ---------------------------------------------------------------------------
__global__ __launch_bounds__(256) void attn_kernel(
    const __bf16* __restrict__ qg, const __bf16* __restrict__ kg,
    const __bf16* __restrict__ vTg, __bf16* __restrict__ yo,
    const int* __restrict__ winp)
{
    const int b = blockIdx.z;
    const int qb = b ? (15 - blockIdx.x) : blockIdx.x;   // heavy+light pairing
    const int q0 = qb * 128;
    const int hh = blockIdx.y;
    const int kvh = hh >> 2;
    const int W = winp[0];

    const int tid  = threadIdx.x;
    const int w    = tid >> 6;
    const int lane = tid & 63;
    const int quad = lane >> 4;
    const int l15  = lane & 15;

    __shared__ __align__(16) __bf16 Ks[2][64 * 64];   // [t][d], XOR-swizzled
    __shared__ __align__(16) __bf16 Vt[2][64 * 64];   // [d][t], XOR-swizzled
    __shared__ __align__(16) __bf16 Ps[4][32 * 72];   // per-wave P

    bf16x8 qf[2][2];
#pragma unroll
    for (int i = 0; i < 2; ++i) {
        size_t qb_ = (((size_t)b * 16 + hh) * 2048 + q0 + w * 32 + i * 16 + l15) * 64;
        qf[i][0] = *(const bf16x8*)(&qg[qb_ + quad * 8]);
        qf[i][1] = *(const bf16x8*)(&qg[qb_ + 32 + quad * 8]);
    }

    f32x4 oacc[2][4];
    float lsum[2][4];
#pragma unroll
    for (int i = 0; i < 2; ++i)
#pragma unroll
        for (int n = 0; n < 4; ++n) {
            oacc[i][n] = (f32x4){0.f, 0.f, 0.f, 0.f};
            lsum[i][n] = 0.f;
        }

    const int lo = q0 - W;
    const int kt_lo = lo > 0 ? (lo >> 6) : 0;
    const int kt_hi = (q0 + 127) >> 6;
    const size_t kvbase = ((size_t)b * 4 + kvh) * 2048 * 64;

    auto stage = [&](int buf, int k0) {
#pragma unroll
        for (int i = 0; i < 2; ++i) {
            int c = i * 256 + tid;
            int rr = c >> 3;
            int jj = (c & 7) ^ (rr & 7);
            cp16(&Ks[buf][c * 8], &kg[kvbase + (size_t)(k0 + rr) * 64 + jj * 8]);
            cp16(&Vt[buf][c * 8], &vTg[kvbase + (size_t)rr * 2048 + k0 + jj * 8]);
        }
    };

    stage(0, kt_lo * 64);
    __syncthreads();

    int cur = 0;
    for (int kt = kt_lo; kt <= kt_hi; ++kt) {
        const int k0 = kt * 64;
        const bool need_mask = (k0 + 63 > q0) || (q0 + 127 - k0 > W);
        if (kt < kt_hi) stage(cur ^ 1, k0 + 64);    // async prefetch

        // QK^T
        f32x4 sacc[2][4];
#pragma unroll
        for (int i = 0; i < 2; ++i)
#pragma unroll
            for (int n = 0; n < 4; ++n) sacc[i][n] = (f32x4){0.f, 0.f, 0.f, 0.f};
        const __bf16* Kc = &Ks[cur][0];
#pragma unroll
        for (int n = 0; n < 4; ++n) {
            int m = n * 16 + l15;
            bf16x8 b0 = *(const bf16x8*)(&Kc[m * 64 + (quad ^ (m & 7)) * 8]);
            bf16x8 b1 = *(const bf16x8*)(&Kc[m * 64 + ((4 + quad) ^ (m & 7)) * 8]);
#pragma unroll
            for (int i = 0; i < 2; ++i) {
                sacc[i][n] = __builtin_amdgcn_mfma_f32_16x16x32_bf16(qf[i][0], b0, sacc[i][n], 0, 0, 0);
                sacc[i][n] = __builtin_amdgcn_mfma_f32_16x16x32_bf16(qf[i][1], b1, sacc[i][n], 0, 0, 0);
            }
        }

        // softmax: p = exp2(s); common factor cancels in o/l
#pragma unroll
        for (int i = 0; i < 2; ++i) {
#pragma unroll
            for (int r = 0; r < 4; ++r) {
                const int row_g = q0 + w * 32 + i * 16 + quad * 4 + r;
#pragma unroll
                for (int n = 0; n < 4; ++n) {
                    float p = exp2f(sacc[i][n][r]);
                    if (need_mask) {
                        int col_g = k0 + n * 16 + l15;
                        bool ok = (col_g <= row_g) && (row_g - col_g <= W);
                        p = ok ? p : 0.f;
                    }
                    lsum[i][r] += p;
                    Ps[w][(i * 16 + quad * 4 + r) * 72 + n * 16 + l15] = (__bf16)p;
                }
            }
        }
        asm volatile("s_waitcnt lgkmcnt(0)" ::: "memory");   // wave-local Ps ordering

        // PV
        const __bf16* Vc = &Vt[cur][0];
#pragma unroll
        for (int ks = 0; ks < 2; ++ks) {
            bf16x8 pfr0 = *(const bf16x8*)(&Ps[w][l15 * 72 + ks * 32 + quad * 8]);
            bf16x8 pfr1 = *(const bf16x8*)(&Ps[w][(16 + l15) * 72 + ks * 32 + quad * 8]);
#pragma unroll
            for (int n = 0; n < 4; ++n) {
                int m = n * 16 + l15;
                bf16x8 bv = *(const bf16x8*)(&Vc[m * 64 + ((ks * 4 + quad) ^ (m & 7)) * 8]);
                oacc[0][n] = __builtin_amdgcn_mfma_f32_16x16x32_bf16(pfr0, bv, oacc[0][n], 0, 0, 0);
                oacc[1][n] = __builtin_amdgcn_mfma_f32_16x16x32_bf16(pfr1, bv, oacc[1][n], 0, 0, 0);
            }
        }

        __syncthreads();   // drains prefetch cp16 + protects buffers
        cur ^= 1;
    }

#pragma unroll
    for (int i = 0; i < 2; ++i) {
#pragma unroll
        for (int r = 0; r < 4; ++r) {
            float l = lsum[i][r];
            l += __shfl_xor(l, 1); l += __shfl_xor(l, 2);
            l += __shfl_xor(l, 4); l += __shfl_xor(l, 8);
            float inv = 1.f / l;
            int t = q0 + w * 32 + i * 16 + quad * 4 + r;
            size_t base = ((size_t)(b * 2048 + t)) * 1024 + hh * 64;
#pragma unroll
            for (int n = 0; n < 4; ++n)
                yo[base + n * 16 + l15] = (__bf16)(oacc[i][n][r] * inv);
        }
    }
}

// ---------------------------------------------------------------------------
// Kernel 4: output projection, 128x64 tiles, BK=64 double-buffered.
// Output dtype via self-sniff of x. Grid: (32, 16).
// ---------------------------------------------------------------------------
__global__ __launch_bounds__(256) void proj_kernel(
    const __bf16* __restrict__ y, const __bf16* __restrict__ WpT,
    void* __restrict__ outp, const void* __restrict__ xraw)
{
    const int isf32 = sniff_block(xraw);
    const int row0 = blockIdx.x * 128;
    const int col0 = blockIdx.y * 64;
    __shared__ __align__(16) __bf16 As[2][128 * 64];
    __shared__ __align__(16) __bf16 Bs[2][64 * 64];

    const int tid  = threadIdx.x;
    const int w    = tid >> 6;
    const int lane = tid & 63;
    const int quad = lane >> 4;
    const int l15  = lane & 15;
    const int wr   = w * 32;

    f32x4 acc[2][4];
#pragma unroll
    for (int mi = 0; mi < 2; ++mi)
#pragma unroll
        for (int nj = 0; nj < 4; ++nj) acc[mi][nj] = (f32x4){0.f, 0.f, 0.f, 0.f};

    auto stage = [&](int buf, int kk) {
#pragma unroll
        for (int i = 0; i < 4; ++i) {
            int c = i * 256 + tid;
            cp16(&As[buf][c * 8], &y[(size_t)(row0 + (c >> 3)) * 1024 + kk + ((c & 7) << 3)]);
        }
#pragma unroll
        for (int i = 0; i < 2; ++i) {
            int c = i * 256 + tid;
            cp16(&Bs[buf][c * 8], &WpT[(size_t)(col0 + (c >> 3)) * 1024 + kk + ((c & 7) << 3)]);
        }
    };

    stage(0, 0);
    __syncthreads();

    for (int kk = 0; kk < 1024; kk += 64) {
        const int cur = (kk >> 6) & 1;
        if (kk + 64 < 1024) stage(cur ^ 1, kk + 64);

        bf16x8 a[2][2], bfr[4][2];
#pragma unroll
        for (int mi = 0; mi < 2; ++mi)
#pragma unroll
            for (int kh = 0; kh < 2; ++kh)
                a[mi][kh] = *(const bf16x8*)(&As[cur][(wr + mi * 16 + l15) * 64 + kh * 32 + quad * 8]);
#pragma unroll
        for (int nj = 0; nj < 4; ++nj)
#pragma unroll
            for (int kh = 0; kh < 2; ++kh)
                bfr[nj][kh] = *(const bf16x8*)(&Bs[cur][(nj * 16 + l15) * 64 + kh * 32 + quad * 8]);
#pragma unroll
        for (int kh = 0; kh < 2; ++kh)
#pragma unroll
            for (int mi = 0; mi < 2; ++mi)
#pragma unroll
                for (int nj = 0; nj < 4; ++nj)
                    acc[mi][nj] = __builtin_amdgcn_mfma_f32_16x16x32_bf16(a[mi][kh], bfr[nj][kh], acc[mi][nj], 0, 0, 0);
        __syncthreads();
    }

#pragma unroll
    for (int mi = 0; mi < 2; ++mi)
#pragma unroll
        for (int r = 0; r < 4; ++r) {
            int row = row0 + wr + mi * 16 + quad * 4 + r;
            if (isf32) {
                float* out = (float*)outp;
#pragma unroll
                for (int nj = 0; nj < 4; ++nj)
                    out[(size_t)row * 1024 + col0 + nj * 16 + l15] = acc[mi][nj][r];
            } else {
                __bf16* out = (__bf16*)outp;
#pragma unroll
                for (int nj = 0; nj < 4; ++nj)
                    out[(size_t)row * 1024 + col0 + nj * 16 + l15] = (__bf16)acc[mi][nj][r];
            }
        }
}

extern "C" void kernel_launch(void* const* d_in, const int* in_sizes, int n_in,
                              void* d_out, int out_size, void* d_ws, size_t ws_size,
                              hipStream_t stream) {
    const int* win = (const int*)d_in[9];

    char* p = (char*)d_ws;
    __bf16* q_ws = (__bf16*)p;                 p += (size_t)4194304 * 2;
    __bf16* k_ws = (__bf16*)p;                 p += (size_t)1048576 * 2;
    __bf16* vT_ws= (__bf16*)p;                 p += (size_t)1048576 * 2;
    __bf16* y_ws = (__bf16*)p;                 p += (size_t)4194304 * 2;
    __bf16* xb   = (__bf16*)p;                 p += (size_t)4194304 * 2;
    __bf16* WqT  = (__bf16*)p;                 p += (size_t)1048576 * 2;
    __bf16* WkT  = (__bf16*)p;                 p += (size_t)262144 * 2;
    __bf16* WvT  = (__bf16*)p;                 p += (size_t)262144 * 2;
    __bf16* WpT  = (__bf16*)p;                 p += (size_t)1048576 * 2;
    __bf16* wgb  = (__bf16*)p;                 p += 256;

    prep_kernel<<<2689, 256, 0, stream>>>(
        d_in[0], d_in[4], d_in[5], d_in[6], d_in[7], d_in[8],
        xb, WqT, WkT, WvT, WpT, wgb);

    qkv_kernel<<<dim3(32, 24), 256, 0, stream>>>(
        xb, d_in[0], d_in[1], d_in[2], d_in[3],
        WqT, WkT, WvT, wgb, q_ws, k_ws, vT_ws);

    attn_kernel<<<dim3(16, 16, 2), 256, 0, stream>>>(q_ws, k_ws, vT_ws, y_ws, win);

    proj_kernel<<<dim3(32, 16), 256, 0, stream>>>(y_ws, WpT, d_out, d_in[0]);
}

// Round 13
// 189.736 us; speedup vs baseline: 1.0708x; 1.0197x over previous
//
#include <hip/hip_runtime.h>

// (B,T,C)=(2,2048,1024), NH=16, NKV=4, HD=64, VEC=32
typedef __bf16 bf16x8 __attribute__((ext_vector_type(8)));
typedef __bf16 bf16x4 __attribute__((ext_vector_type(4)));
typedef float f32x4 __attribute__((ext_vector_type(4)));

__device__ inline float tof(float v) { return v; }
__device__ inline float tof(__bf16 v) { return (float)v; }

__device__ inline bf16x8 load8(const __bf16* p) { return *(const bf16x8*)p; }
__device__ inline bf16x8 load8(const float* p) {
    const float4 a = *(const float4*)p;
    const float4 b = *(const float4*)(p + 4);
    bf16x8 r;
    r[0] = (__bf16)a.x; r[1] = (__bf16)a.y; r[2] = (__bf16)a.z; r[3] = (__bf16)a.w;
    r[4] = (__bf16)b.x; r[5] = (__bf16)b.y; r[6] = (__bf16)b.z; r[7] = (__bf16)b.w;
    return r;
}

__device__ __forceinline__ float ldT(const void* p, size_t i, int isf32) {
    return isf32 ? ((const float*)p)[i] : tof(((const __bf16*)p)[i]);
}

// async global->LDS, 16B per lane (dest = wave-uniform base + lane*16)
__device__ __forceinline__ void cp16(__bf16* lds, const __bf16* g) {
    __builtin_amdgcn_global_load_lds((__attribute__((address_space(1))) void*)g,
                                     (__attribute__((address_space(3))) void*)lds,
                                     16, 0, 0);
}

// per-block dtype sniff (one barrier): fp32-as-bf16 shows wild exponents
__device__ __forceinline__ int sniff_block(const void* xraw) {
    const unsigned short* xs = (const unsigned short*)xraw;
    int tid = threadIdx.x;
    int bad = 0;
#pragma unroll
    for (int k = 0; k < 2; ++k) {
        float v = __uint_as_float(((unsigned int)xs[tid * 2 + k]) << 16);
        float a = fabsf(v);
        if (!(a <= 1e4f) || (a != 0.f && a < 1e-6f)) bad = 1;
    }
    return __syncthreads_count(bad) > 32;
}

// ---------------------------------------------------------------------------
// Kernel 1: prep — convert x to bf16, transpose weights to B^T bf16, Wgate.
// Grid: 2689. [0,2048) x-convert, [2048,2688) transpose, 2688 = Wg.
// ---------------------------------------------------------------------------
template <typename T>
__device__ __forceinline__ void prep_body(
    const T* __restrict__ x,
    const T* __restrict__ Wq, const T* __restrict__ Wk,
    const T* __restrict__ Wv, const T* __restrict__ Wp, const T* __restrict__ Wg,
    __bf16* __restrict__ xb,
    __bf16* __restrict__ WqT, __bf16* __restrict__ WkT,
    __bf16* __restrict__ WvT, __bf16* __restrict__ WpT,
    __bf16* __restrict__ wgb, __bf16* tile)
{
    const int b = blockIdx.x, tid = threadIdx.x;
    if (b < 2048) {
        int g = b * 256 + tid;     // 8 elems each, 4.19M total
        *(bf16x8*)(xb + (size_t)g * 8) = load8(x + (size_t)g * 8);
    } else if (b < 2688) {         // 64x64 tile transpose
        int idx = b - 2048;
        const T* src; __bf16* dst; int C;
        if (idx < 256)      { src = Wq; dst = WqT; C = 1024; }
        else if (idx < 320) { src = Wk; dst = WkT; C = 256;  idx -= 256; }
        else if (idx < 384) { src = Wv; dst = WvT; C = 256;  idx -= 320; }
        else                { src = Wp; dst = WpT; C = 1024; idx -= 384; }
        const int ctiles = C >> 6;
        const int r0 = (idx / ctiles) * 64, c0 = (idx % ctiles) * 64;
#pragma unroll
        for (int i = 0; i < 2; ++i) {
            int c = tid + i * 256, ir = c >> 3, ic = (c & 7) * 8;
            *(bf16x8*)(&tile[ir * 72 + ic]) = load8(src + (size_t)(r0 + ir) * C + c0 + ic);
        }
        __syncthreads();
#pragma unroll
        for (int i = 0; i < 2; ++i) {
            int c = tid + i * 256, orr = c >> 3, okc = (c & 7) * 8;
            bf16x8 v;
#pragma unroll
            for (int j = 0; j < 8; ++j) v[j] = tile[(okc + j) * 72 + orr];
            *(bf16x8*)(dst + (size_t)(c0 + orr) * 1024 + r0 + okc) = v;
        }
    } else if (tid < 128) {
        wgb[tid] = (__bf16)tof(Wg[tid]);
    }
}

__global__ __launch_bounds__(256) void prep_kernel(
    const void* x,
    const void* Wq, const void* Wk, const void* Wv, const void* Wp, const void* Wg,
    __bf16* xb,
    __bf16* WqT, __bf16* WkT, __bf16* WvT, __bf16* WpT, __bf16* wgb)
{
    __shared__ __bf16 tile[64 * 72];
    const int isf32 = sniff_block(x);
    if (isf32) {
        prep_body<float>((const float*)x, (const float*)Wq, (const float*)Wk,
                         (const float*)Wv, (const float*)Wp, (const float*)Wg,
                         xb, WqT, WkT, WvT, WpT, wgb, tile);
    } else {
        prep_body<__bf16>((const __bf16*)x, (const __bf16*)Wq, (const __bf16*)Wk,
                          (const __bf16*)Wv, (const __bf16*)Wp, (const __bf16*)Wg,
                          xb, WqT, WkT, WvT, WpT, wgb, tile);
    }
}

// ---------------------------------------------------------------------------
// Kernel 2: QKV GEMM, 128x64 tiles, BK=64, cp16 double-buffered staging
// (48KB -> 3 blocks/CU). Gate via MFMA at kk==0. q pre-scaled by log2e/8.
// V written transposed vT[b][kvh][d][t]. Grid (32,24).
// ---------------------------------------------------------------------------
__global__ __launch_bounds__(256) void qkv_kernel(
    const __bf16* __restrict__ xb,
    const void* __restrict__ xraw, const void* __restrict__ veraw,
    const void* __restrict__ cosraw, const void* __restrict__ sinraw,
    const __bf16* __restrict__ WqT, const __bf16* __restrict__ WkT,
    const __bf16* __restrict__ WvT, const __bf16* __restrict__ wgb,
    __bf16* __restrict__ qo, __bf16* __restrict__ ko, __bf16* __restrict__ vTo)
{
    const int isf32 = sniff_block(xraw);   // for epilogue ve/cos/sin reads

    const int row0 = blockIdx.x * 128;
    const int cb = blockIdx.y;
    const __bf16* BT; int col0, h, mode;
    if (cb < 16)      { BT = WqT; col0 = cb * 64;        h = cb;      mode = 0; }
    else if (cb < 20) { BT = WkT; col0 = (cb - 16) * 64; h = cb - 16; mode = 1; }
    else              { BT = WvT; col0 = (cb - 20) * 64; h = cb - 20; mode = 2; }

    __shared__ __align__(16) __bf16 As[2][128 * 64];
    __shared__ __align__(16) __bf16 Bs[2][64 * 64];

    const int tid  = threadIdx.x;
    const int w    = tid >> 6;
    const int lane = tid & 63;
    const int quad = lane >> 4;
    const int l15  = lane & 15;
    const int wr   = w * 32;

    f32x4 acc[2][4];
#pragma unroll
    for (int mi = 0; mi < 2; ++mi)
#pragma unroll
        for (int nj = 0; nj < 4; ++nj) acc[mi][nj] = (f32x4){0.f, 0.f, 0.f, 0.f};

    // gate B-fragment: Wg[k=quad*8+j][n=l15], cols >=4 zero
    bf16x8 wgB;
#pragma unroll
    for (int j = 0; j < 8; ++j) wgB[j] = (__bf16)0.f;
    if (mode == 2 && l15 < 4) {
#pragma unroll
        for (int j = 0; j < 8; ++j) wgB[j] = wgb[(quad * 8 + j) * 4 + l15];
    }
    f32x4 zacc[2];
    zacc[0] = (f32x4){0.f, 0.f, 0.f, 0.f};
    zacc[1] = (f32x4){0.f, 0.f, 0.f, 0.f};

    auto stage = [&](int buf, int kk) {
#pragma unroll
        for (int i = 0; i < 4; ++i) {      // A: 128x64 = 1024 chunks
            int c = i * 256 + tid;
            cp16(&As[buf][c * 8], &xb[(size_t)(row0 + (c >> 3)) * 1024 + kk + ((c & 7) << 3)]);
        }
#pragma unroll
        for (int i = 0; i < 2; ++i) {      // B: 64x64 = 512 chunks
            int c = i * 256 + tid;
            cp16(&Bs[buf][c * 8], &BT[(size_t)(col0 + (c >> 3)) * 1024 + kk + ((c & 7) << 3)]);
        }
    };

    stage(0, 0);
    __syncthreads();

    for (int kk = 0; kk < 1024; kk += 64) {
        const int cur = (kk >> 6) & 1;
        if (kk + 64 < 1024) stage(cur ^ 1, kk + 64);   // async prefetch

        bf16x8 a[2][2], bfr[4][2];
#pragma unroll
        for (int mi = 0; mi < 2; ++mi)
#pragma unroll
            for (int kh = 0; kh < 2; ++kh)
                a[mi][kh] = *(const bf16x8*)(&As[cur][(wr + mi * 16 + l15) * 64 + kh * 32 + quad * 8]);
#pragma unroll
        for (int nj = 0; nj < 4; ++nj)
#pragma unroll
            for (int kh = 0; kh < 2; ++kh)
                bfr[nj][kh] = *(const bf16x8*)(&Bs[cur][(nj * 16 + l15) * 64 + kh * 32 + quad * 8]);

        if (mode == 2 && kk == 0) {        // gate z = x[:,0:32] @ Wg
            zacc[0] = __builtin_amdgcn_mfma_f32_16x16x32_bf16(a[0][0], wgB, zacc[0], 0, 0, 0);
            zacc[1] = __builtin_amdgcn_mfma_f32_16x16x32_bf16(a[1][0], wgB, zacc[1], 0, 0, 0);
        }
#pragma unroll
        for (int kh = 0; kh < 2; ++kh)
#pragma unroll
            for (int mi = 0; mi < 2; ++mi)
#pragma unroll
                for (int nj = 0; nj < 4; ++nj)
                    acc[mi][nj] = __builtin_amdgcn_mfma_f32_16x16x32_bf16(a[mi][kh], bfr[nj][kh], acc[mi][nj], 0, 0, 0);
        __syncthreads();
    }

    if (mode < 2) {
        __bf16* dst = (mode == 0) ? qo : ko;
        const int nh = (mode == 0) ? 16 : 4;
        const float post = (mode == 0) ? 0.18033688f : 1.0f;   // fold softmax scale into q
#pragma unroll
        for (int mi = 0; mi < 2; ++mi) {
#pragma unroll
            for (int r = 0; r < 4; ++r) {
                int row = row0 + wr + mi * 16 + quad * 4 + r;
                int b = row >> 11, t = row & 2047;
                float c0 = ldT(cosraw, t * 32 + l15, isf32);
                float c1 = ldT(cosraw, t * 32 + 16 + l15, isf32);
                float s0 = ldT(sinraw, t * 32 + l15, isf32);
                float s1 = ldT(sinraw, t * 32 + 16 + l15, isf32);
                float v0 =  c0 * acc[mi][0][r] + s0 * acc[mi][2][r];
                float v1 =  c1 * acc[mi][1][r] + s1 * acc[mi][3][r];
                float v2 = -s0 * acc[mi][0][r] + c0 * acc[mi][2][r];
                float v3 = -s1 * acc[mi][1][r] + c1 * acc[mi][3][r];
                float ss = v0 * v0 + v1 * v1 + v2 * v2 + v3 * v3;
                ss += __shfl_xor(ss, 1); ss += __shfl_xor(ss, 2);
                ss += __shfl_xor(ss, 4); ss += __shfl_xor(ss, 8);
                float sc = rsqrtf(ss * (1.f / 64.f) + 1.1920929e-7f) * post;
                size_t base = (((size_t)b * nh + h) * 2048 + t) * 64;
                dst[base + 0 * 16 + l15] = (__bf16)(v0 * sc);
                dst[base + 1 * 16 + l15] = (__bf16)(v1 * sc);
                dst[base + 2 * 16 + l15] = (__bf16)(v2 * sc);
                dst[base + 3 * 16 + l15] = (__bf16)(v3 * sc);
            }
        }
    } else {
        // vT[(b*4+h)*64 + d][t], packed 4 consecutive t per store
#pragma unroll
        for (int mi = 0; mi < 2; ++mi) {
            int rowb = row0 + wr + mi * 16 + quad * 4;
            int b = rowb >> 11, t0 = rowb & 2047;
            float gg[4];
#pragma unroll
            for (int r = 0; r < 4; ++r) {
                float zv = __shfl(zacc[mi][r], quad * 16 + h);
                gg[r] = 2.f / (1.f + __expf(-zv));
            }
#pragma unroll
            for (int nj = 0; nj < 4; ++nj) {
                int d = nj * 16 + l15;
                bf16x4 pack;
#pragma unroll
                for (int r = 0; r < 4; ++r) {
                    int row = rowb + r;
                    float vev = ldT(veraw, (size_t)row * 256 + h * 64 + d, isf32);
                    pack[r] = (__bf16)(acc[mi][nj][r] + gg[r] * vev);
                }
                size_t a = (((size_t)b * 4 + h) * 64 + d) * 2048 + t0;
                *(bf16x4*)(&vTo[a]) = pack;
            }
        }
    }
}

// ---------------------------------------------------------------------------
// Kernel 3: sliding-window causal GQA flash attention, TRANSPOSED-SCORE form.
// QK^T computed as S^T (A=K-frag, B=Q-frag) so C-layout lane = q-row:
//   - P staged as 8 packed ds_write_b64 (vs 32 b16), swizzled 16B chunks
//   - PV as O^T = Vt-frag (A) x P-frag (B); lsum is per-lane, 2-shfl reduce
// K/V^T cp16 XOR-swizzled, double-buffered, one barrier/tile. Grid (16,16,2).
// ---------------------------------------------------------------------------
__global__ __launch_bounds__(256) void attn_kernel(
    const __bf16* __restrict__ qg, const __bf16* __restrict__ kg,
    const __bf16* __restrict__ vTg, __bf16* __restrict__ yo,
    const int* __restrict__ winp)
{
    const int b = blockIdx.z;
    const int qb = b ? (15 - blockIdx.x) : blockIdx.x;   // heavy+light pairing
    const int q0 = qb * 128;
    const int hh = blockIdx.y;
    const int kvh = hh >> 2;
    const int W = winp[0];

    const int tid  = threadIdx.x;
    const int w    = tid >> 6;
    const int lane = tid & 63;
    const int quad = lane >> 4;
    const int l15  = lane & 15;

    __shared__ __align__(16) __bf16 Ks[2][64 * 64];   // [t][d], XOR-swizzled
    __shared__ __align__(16) __bf16 Vt[2][64 * 64];   // [d][t], XOR-swizzled
    __shared__ __align__(16) __bf16 Ps[4][32 * 64];   // per-wave P[q][t], swizzled

    bf16x8 qf[2][2];   // B-frag: lane n = q-row, regs k = d
#pragma unroll
    for (int i = 0; i < 2; ++i) {
        size_t qb_ = (((size_t)b * 16 + hh) * 2048 + q0 + w * 32 + i * 16 + l15) * 64;
        qf[i][0] = *(const bf16x8*)(&qg[qb_ + quad * 8]);
        qf[i][1] = *(const bf16x8*)(&qg[qb_ + 32 + quad * 8]);
    }

    f32x4 oacc[2][4];   // O^T: lane = q-row, [dg] d-groups, regs = d in group
    float lsum[2] = {0.f, 0.f};
#pragma unroll
    for (int i = 0; i < 2; ++i)
#pragma unroll
        for (int dg = 0; dg < 4; ++dg) oacc[i][dg] = (f32x4){0.f, 0.f, 0.f, 0.f};

    const int lo = q0 - W;
    const int kt_lo = lo > 0 ? (lo >> 6) : 0;
    const int kt_hi = (q0 + 127) >> 6;
    const size_t kvbase = ((size_t)b * 4 + kvh) * 2048 * 64;

    auto stage = [&](int buf, int k0) {
#pragma unroll
        for (int i = 0; i < 2; ++i) {
            int c = i * 256 + tid;
            int rr = c >> 3;
            int jj = (c & 7) ^ (rr & 7);
            cp16(&Ks[buf][c * 8], &kg[kvbase + (size_t)(k0 + rr) * 64 + jj * 8]);
            cp16(&Vt[buf][c * 8], &vTg[kvbase + (size_t)rr * 2048 + k0 + jj * 8]);
        }
    };

    stage(0, kt_lo * 64);
    __syncthreads();

    int cur = 0;
    for (int kt = kt_lo; kt <= kt_hi; ++kt) {
        const int k0 = kt * 64;
        const bool need_mask = (k0 + 63 > q0) || (q0 + 127 - k0 > W);
        if (kt < kt_hi) stage(cur ^ 1, k0 + 64);    // async prefetch

        // QK^T transposed: sacc[i][g] = S^T, row = t_local g*16+quad*4+r, col = q
        f32x4 sacc[2][4];
#pragma unroll
        for (int i = 0; i < 2; ++i)
#pragma unroll
            for (int g = 0; g < 4; ++g) sacc[i][g] = (f32x4){0.f, 0.f, 0.f, 0.f};
        const __bf16* Kc = &Ks[cur][0];
#pragma unroll
        for (int g = 0; g < 4; ++g) {
            int t = g * 16 + l15;
            bf16x8 kf0 = *(const bf16x8*)(&Kc[t * 64 + (quad ^ (t & 7)) * 8]);
            bf16x8 kf1 = *(const bf16x8*)(&Kc[t * 64 + ((4 + quad) ^ (t & 7)) * 8]);
#pragma unroll
            for (int i = 0; i < 2; ++i) {
                sacc[i][g] = __builtin_amdgcn_mfma_f32_16x16x32_bf16(kf0, qf[i][0], sacc[i][g], 0, 0, 0);
                sacc[i][g] = __builtin_amdgcn_mfma_f32_16x16x32_bf16(kf1, qf[i][1], sacc[i][g], 0, 0, 0);
            }
        }

        // softmax (p = exp2(s), q pre-scaled); packed b64 stores into Ps[q][t]
#pragma unroll
        for (int i = 0; i < 2; ++i) {
            const int qrow = q0 + w * 32 + i * 16 + l15;
#pragma unroll
            for (int g = 0; g < 4; ++g) {
                bf16x4 pk;
#pragma unroll
                for (int r = 0; r < 4; ++r) {
                    float p = exp2f(sacc[i][g][r]);
                    if (need_mask) {
                        int col = k0 + g * 16 + quad * 4 + r;
                        bool ok = (col <= qrow) && (qrow - col <= W);
                        p = ok ? p : 0.f;
                    }
                    lsum[i] += p;
                    pk[r] = (__bf16)p;
                }
                int ch = ((g * 2 + (quad >> 1)) ^ (l15 & 7)) * 8 + (quad & 1) * 4;
                *(bf16x4*)(&Ps[w][(i * 16 + l15) * 64 + ch]) = pk;
            }
        }
        asm volatile("s_waitcnt lgkmcnt(0)" ::: "memory");   // wave-local Ps ordering

        // PV: O^T = Vt(A) x P(B); Vt-frags shared across both q-groups
        const __bf16* Vc = &Vt[cur][0];
#pragma unroll
        for (int ks = 0; ks < 2; ++ks) {
            bf16x8 pB[2];
#pragma unroll
            for (int i = 0; i < 2; ++i)
                pB[i] = *(const bf16x8*)(&Ps[w][(i * 16 + l15) * 64 + ((ks * 4 + quad) ^ (l15 & 7)) * 8]);
#pragma unroll
            for (int dg = 0; dg < 4; ++dg) {
                int m = dg * 16 + l15;
                bf16x8 av = *(const bf16x8*)(&Vc[m * 64 + ((ks * 4 + quad) ^ (m & 7)) * 8]);
                oacc[0][dg] = __builtin_amdgcn_mfma_f32_16x16x32_bf16(av, pB[0], oacc[0][dg], 0, 0, 0);
                oacc[1][dg] = __builtin_amdgcn_mfma_f32_16x16x32_bf16(av, pB[1], oacc[1][dg], 0, 0, 0);
            }
        }

        __syncthreads();   // drains prefetch cp16 + protects buffers
        cur ^= 1;
    }

#pragma unroll
    for (int i = 0; i < 2; ++i) {
        float l = lsum[i];
        l += __shfl_xor(l, 16); l += __shfl_xor(l, 32);   // sum over quads (same q)
        float inv = 1.f / l;
        int q = q0 + w * 32 + i * 16 + l15;
        size_t base = ((size_t)(b * 2048 + q)) * 1024 + hh * 64;
#pragma unroll
        for (int dg = 0; dg < 4; ++dg) {
            bf16x4 ov;
#pragma unroll
            for (int r = 0; r < 4; ++r) ov[r] = (__bf16)(oacc[i][dg][r] * inv);
            *(bf16x4*)(&yo[base + dg * 16 + quad * 4]) = ov;
        }
    }
}

// ---------------------------------------------------------------------------
// Kernel 4: output projection, 128x64 tiles, BK=64 double-buffered.
// Output dtype via self-sniff of x. Grid: (32, 16).
// ---------------------------------------------------------------------------
__global__ __launch_bounds__(256) void proj_kernel(
    const __bf16* __restrict__ y, const __bf16* __restrict__ WpT,
    void* __restrict__ outp, const void* __restrict__ xraw)
{
    const int isf32 = sniff_block(xraw);
    const int row0 = blockIdx.x * 128;
    const int col0 = blockIdx.y * 64;
    __shared__ __align__(16) __bf16 As[2][128 * 64];
    __shared__ __align__(16) __bf16 Bs[2][64 * 64];

    const int tid  = threadIdx.x;
    const int w    = tid >> 6;
    const int lane = tid & 63;
    const int quad = lane >> 4;
    const int l15  = lane & 15;
    const int wr   = w * 32;

    f32x4 acc[2][4];
#pragma unroll
    for (int mi = 0; mi < 2; ++mi)
#pragma unroll
        for (int nj = 0; nj < 4; ++nj) acc[mi][nj] = (f32x4){0.f, 0.f, 0.f, 0.f};

    auto stage = [&](int buf, int kk) {
#pragma unroll
        for (int i = 0; i < 4; ++i) {
            int c = i * 256 + tid;
            cp16(&As[buf][c * 8], &y[(size_t)(row0 + (c >> 3)) * 1024 + kk + ((c & 7) << 3)]);
        }
#pragma unroll
        for (int i = 0; i < 2; ++i) {
            int c = i * 256 + tid;
            cp16(&Bs[buf][c * 8], &WpT[(size_t)(col0 + (c >> 3)) * 1024 + kk + ((c & 7) << 3)]);
        }
    };

    stage(0, 0);
    __syncthreads();

    for (int kk = 0; kk < 1024; kk += 64) {
        const int cur = (kk >> 6) & 1;
        if (kk + 64 < 1024) stage(cur ^ 1, kk + 64);

        bf16x8 a[2][2], bfr[4][2];
#pragma unroll
        for (int mi = 0; mi < 2; ++mi)
#pragma unroll
            for (int kh = 0; kh < 2; ++kh)
                a[mi][kh] = *(const bf16x8*)(&As[cur][(wr + mi * 16 + l15) * 64 + kh * 32 + quad * 8]);
#pragma unroll
        for (int nj = 0; nj < 4; ++nj)
#pragma unroll
            for (int kh = 0; kh < 2; ++kh)
                bfr[nj][kh] = *(const bf16x8*)(&Bs[cur][(nj * 16 + l15) * 64 + kh * 32 + quad * 8]);
#pragma unroll
        for (int kh = 0; kh < 2; ++kh)
#pragma unroll
            for (int mi = 0; mi < 2; ++mi)
#pragma unroll
                for (int nj = 0; nj < 4; ++nj)
                    acc[mi][nj] = __builtin_amdgcn_mfma_f32_16x16x32_bf16(a[mi][kh], bfr[nj][kh], acc[mi][nj], 0, 0, 0);
        __syncthreads();
    }

#pragma unroll
    for (int mi = 0; mi < 2; ++mi)
#pragma unroll
        for (int r = 0; r < 4; ++r) {
            int row = row0 + wr + mi * 16 + quad * 4 + r;
            if (isf32) {
                float* out = (float*)outp;
#pragma unroll
                for (int nj = 0; nj < 4; ++nj)
                    out[(size_t)row * 1024 + col0 + nj * 16 + l15] = acc[mi][nj][r];
            } else {
                __bf16* out = (__bf16*)outp;
#pragma unroll
                for (int nj = 0; nj < 4; ++nj)
                    out[(size_t)row * 1024 + col0 + nj * 16 + l15] = (__bf16)acc[mi][nj][r];
            }
        }
}

extern "C" void kernel_launch(void* const* d_in, const int* in_sizes, int n_in,
                              void* d_out, int out_size, void* d_ws, size_t ws_size,
                              hipStream_t stream) {
    const int* win = (const int*)d_in[9];

    char* p = (char*)d_ws;
    __bf16* q_ws = (__bf16*)p;                 p += (size_t)4194304 * 2;
    __bf16* k_ws = (__bf16*)p;                 p += (size_t)1048576 * 2;
    __bf16* vT_ws= (__bf16*)p;                 p += (size_t)1048576 * 2;
    __bf16* y_ws = (__bf16*)p;                 p += (size_t)4194304 * 2;
    __bf16* xb   = (__bf16*)p;                 p += (size_t)4194304 * 2;
    __bf16* WqT  = (__bf16*)p;                 p += (size_t)1048576 * 2;
    __bf16* WkT  = (__bf16*)p;                 p += (size_t)262144 * 2;
    __bf16* WvT  = (__bf16*)p;                 p += (size_t)262144 * 2;
    __bf16* WpT  = (__bf16*)p;                 p += (size_t)1048576 * 2;
    __bf16* wgb  = (__bf16*)p;                 p += 256;

    prep_kernel<<<2689, 256, 0, stream>>>(
        d_in[0], d_in[4], d_in[5], d_in[6], d_in[7], d_in[8],
        xb, WqT, WkT, WvT, WpT, wgb);

    qkv_kernel<<<dim3(32, 24), 256, 0, stream>>>(
        xb, d_in[0], d_in[1], d_in[2], d_in[3],
        WqT, WkT, WvT, wgb, q_ws, k_ws, vT_ws);

    attn_kernel<<<dim3(16, 16, 2), 256, 0, stream>>>(q_ws, k_ws, vT_ws, y_ws, win);

    proj_kernel<<<dim3(32, 16), 256, 0, stream>>>(y_ws, WpT, d_out, d_in[0]);
}

// Round 14
// 186.629 us; speedup vs baseline: 1.0886x; 1.0166x over previous
//
#include <hip/hip_runtime.h>

// (B,T,C)=(2,2048,1024), NH=16, NKV=4, HD=64, VEC=32
typedef __bf16 bf16x8 __attribute__((ext_vector_type(8)));
typedef __bf16 bf16x4 __attribute__((ext_vector_type(4)));
typedef float f32x4 __attribute__((ext_vector_type(4)));

__device__ inline float tof(float v) { return v; }
__device__ inline float tof(__bf16 v) { return (float)v; }

__device__ inline bf16x8 load8(const __bf16* p) { return *(const bf16x8*)p; }
__device__ inline bf16x8 load8(const float* p) {
    const float4 a = *(const float4*)p;
    const float4 b = *(const float4*)(p + 4);
    bf16x8 r;
    r[0] = (__bf16)a.x; r[1] = (__bf16)a.y; r[2] = (__bf16)a.z; r[3] = (__bf16)a.w;
    r[4] = (__bf16)b.x; r[5] = (__bf16)b.y; r[6] = (__bf16)b.z; r[7] = (__bf16)b.w;
    return r;
}

__device__ __forceinline__ float ldT(const void* p, size_t i, int isf32) {
    return isf32 ? ((const float*)p)[i] : tof(((const __bf16*)p)[i]);
}

// async global->LDS, 16B per lane (dest = wave-uniform base + lane*16)
__device__ __forceinline__ void cp16(__bf16* lds, const __bf16* g) {
    __builtin_amdgcn_global_load_lds((__attribute__((address_space(1))) void*)g,
                                     (__attribute__((address_space(3))) void*)lds,
                                     16, 0, 0);
}

// per-block dtype sniff (one barrier): fp32-as-bf16 shows wild exponents
__device__ __forceinline__ int sniff_block(const void* xraw) {
    const unsigned short* xs = (const unsigned short*)xraw;
    int tid = threadIdx.x;
    int bad = 0;
#pragma unroll
    for (int k = 0; k < 2; ++k) {
        float v = __uint_as_float(((unsigned int)xs[tid * 2 + k]) << 16);
        float a = fabsf(v);
        if (!(a <= 1e4f) || (a != 0.f && a < 1e-6f)) bad = 1;
    }
    return __syncthreads_count(bad) > 32;
}

// ---------------------------------------------------------------------------
// Kernel 1: prep — convert x to bf16, transpose weights to B^T bf16, Wgate.
// Grid: 2689. [0,2048) x-convert, [2048,2688) transpose, 2688 = Wg.
// ---------------------------------------------------------------------------
template <typename T>
__device__ __forceinline__ void prep_body(
    const T* __restrict__ x,
    const T* __restrict__ Wq, const T* __restrict__ Wk,
    const T* __restrict__ Wv, const T* __restrict__ Wp, const T* __restrict__ Wg,
    __bf16* __restrict__ xb,
    __bf16* __restrict__ WqT, __bf16* __restrict__ WkT,
    __bf16* __restrict__ WvT, __bf16* __restrict__ WpT,
    __bf16* __restrict__ wgb, __bf16* tile)
{
    const int b = blockIdx.x, tid = threadIdx.x;
    if (b < 2048) {
        int g = b * 256 + tid;     // 8 elems each, 4.19M total
        *(bf16x8*)(xb + (size_t)g * 8) = load8(x + (size_t)g * 8);
    } else if (b < 2688) {         // 64x64 tile transpose
        int idx = b - 2048;
        const T* src; __bf16* dst; int C;
        if (idx < 256)      { src = Wq; dst = WqT; C = 1024; }
        else if (idx < 320) { src = Wk; dst = WkT; C = 256;  idx -= 256; }
        else if (idx < 384) { src = Wv; dst = WvT; C = 256;  idx -= 320; }
        else                { src = Wp; dst = WpT; C = 1024; idx -= 384; }
        const int ctiles = C >> 6;
        const int r0 = (idx / ctiles) * 64, c0 = (idx % ctiles) * 64;
#pragma unroll
        for (int i = 0; i < 2; ++i) {
            int c = tid + i * 256, ir = c >> 3, ic = (c & 7) * 8;
            *(bf16x8*)(&tile[ir * 72 + ic]) = load8(src + (size_t)(r0 + ir) * C + c0 + ic);
        }
        __syncthreads();
#pragma unroll
        for (int i = 0; i < 2; ++i) {
            int c = tid + i * 256, orr = c >> 3, okc = (c & 7) * 8;
            bf16x8 v;
#pragma unroll
            for (int j = 0; j < 8; ++j) v[j] = tile[(okc + j) * 72 + orr];
            *(bf16x8*)(dst + (size_t)(c0 + orr) * 1024 + r0 + okc) = v;
        }
    } else if (tid < 128) {
        wgb[tid] = (__bf16)tof(Wg[tid]);
    }
}

__global__ __launch_bounds__(256) void prep_kernel(
    const void* x,
    const void* Wq, const void* Wk, const void* Wv, const void* Wp, const void* Wg,
    __bf16* xb,
    __bf16* WqT, __bf16* WkT, __bf16* WvT, __bf16* WpT, __bf16* wgb)
{
    __shared__ __bf16 tile[64 * 72];
    const int isf32 = sniff_block(x);
    if (isf32) {
        prep_body<float>((const float*)x, (const float*)Wq, (const float*)Wk,
                         (const float*)Wv, (const float*)Wp, (const float*)Wg,
                         xb, WqT, WkT, WvT, WpT, wgb, tile);
    } else {
        prep_body<__bf16>((const __bf16*)x, (const __bf16*)Wq, (const __bf16*)Wk,
                          (const __bf16*)Wv, (const __bf16*)Wp, (const __bf16*)Wg,
                          xb, WqT, WkT, WvT, WpT, wgb, tile);
    }
}

// ---------------------------------------------------------------------------
// Kernel 2: QKV GEMM, 128x64 tiles, BK=64, cp16 double-buffered staging
// (48KB -> 3 blocks/CU). Gate via MFMA at kk==0. q pre-scaled by log2e/8.
// V written transposed vT[b][kvh][d][t]. Grid (32,24).
// ---------------------------------------------------------------------------
__global__ __launch_bounds__(256) void qkv_kernel(
    const __bf16* __restrict__ xb,
    const void* __restrict__ xraw, const void* __restrict__ veraw,
    const void* __restrict__ cosraw, const void* __restrict__ sinraw,
    const __bf16* __restrict__ WqT, const __bf16* __restrict__ WkT,
    const __bf16* __restrict__ WvT, const __bf16* __restrict__ wgb,
    __bf16* __restrict__ qo, __bf16* __restrict__ ko, __bf16* __restrict__ vTo)
{
    const int isf32 = sniff_block(xraw);   // for epilogue ve/cos/sin reads

    const int row0 = blockIdx.x * 128;
    const int cb = blockIdx.y;
    const __bf16* BT; int col0, h, mode;
    if (cb < 16)      { BT = WqT; col0 = cb * 64;        h = cb;      mode = 0; }
    else if (cb < 20) { BT = WkT; col0 = (cb - 16) * 64; h = cb - 16; mode = 1; }
    else              { BT = WvT; col0 = (cb - 20) * 64; h = cb - 20; mode = 2; }

    __shared__ __align__(16) __bf16 As[2][128 * 64];
    __shared__ __align__(16) __bf16 Bs[2][64 * 64];

    const int tid  = threadIdx.x;
    const int w    = tid >> 6;
    const int lane = tid & 63;
    const int quad = lane >> 4;
    const int l15  = lane & 15;
    const int wr   = w * 32;

    f32x4 acc[2][4];
#pragma unroll
    for (int mi = 0; mi < 2; ++mi)
#pragma unroll
        for (int nj = 0; nj < 4; ++nj) acc[mi][nj] = (f32x4){0.f, 0.f, 0.f, 0.f};

    // gate B-fragment: Wg[k=quad*8+j][n=l15], cols >=4 zero
    bf16x8 wgB;
#pragma unroll
    for (int j = 0; j < 8; ++j) wgB[j] = (__bf16)0.f;
    if (mode == 2 && l15 < 4) {
#pragma unroll
        for (int j = 0; j < 8; ++j) wgB[j] = wgb[(quad * 8 + j) * 4 + l15];
    }
    f32x4 zacc[2];
    zacc[0] = (f32x4){0.f, 0.f, 0.f, 0.f};
    zacc[1] = (f32x4){0.f, 0.f, 0.f, 0.f};

    auto stage = [&](int buf, int kk) {
#pragma unroll
        for (int i = 0; i < 4; ++i) {      // A: 128x64 = 1024 chunks
            int c = i * 256 + tid;
            cp16(&As[buf][c * 8], &xb[(size_t)(row0 + (c >> 3)) * 1024 + kk + ((c & 7) << 3)]);
        }
#pragma unroll
        for (int i = 0; i < 2; ++i) {      // B: 64x64 = 512 chunks
            int c = i * 256 + tid;
            cp16(&Bs[buf][c * 8], &BT[(size_t)(col0 + (c >> 3)) * 1024 + kk + ((c & 7) << 3)]);
        }
    };

    stage(0, 0);
    __syncthreads();

    for (int kk = 0; kk < 1024; kk += 64) {
        const int cur = (kk >> 6) & 1;
        if (kk + 64 < 1024) stage(cur ^ 1, kk + 64);   // async prefetch

        bf16x8 a[2][2], bfr[4][2];
#pragma unroll
        for (int mi = 0; mi < 2; ++mi)
#pragma unroll
            for (int kh = 0; kh < 2; ++kh)
                a[mi][kh] = *(const bf16x8*)(&As[cur][(wr + mi * 16 + l15) * 64 + kh * 32 + quad * 8]);
#pragma unroll
        for (int nj = 0; nj < 4; ++nj)
#pragma unroll
            for (int kh = 0; kh < 2; ++kh)
                bfr[nj][kh] = *(const bf16x8*)(&Bs[cur][(nj * 16 + l15) * 64 + kh * 32 + quad * 8]);

        if (mode == 2 && kk == 0) {        // gate z = x[:,0:32] @ Wg
            zacc[0] = __builtin_amdgcn_mfma_f32_16x16x32_bf16(a[0][0], wgB, zacc[0], 0, 0, 0);
            zacc[1] = __builtin_amdgcn_mfma_f32_16x16x32_bf16(a[1][0], wgB, zacc[1], 0, 0, 0);
        }
#pragma unroll
        for (int kh = 0; kh < 2; ++kh)
#pragma unroll
            for (int mi = 0; mi < 2; ++mi)
#pragma unroll
                for (int nj = 0; nj < 4; ++nj)
                    acc[mi][nj] = __builtin_amdgcn_mfma_f32_16x16x32_bf16(a[mi][kh], bfr[nj][kh], acc[mi][nj], 0, 0, 0);
        __syncthreads();
    }

    if (mode < 2) {
        __bf16* dst = (mode == 0) ? qo : ko;
        const int nh = (mode == 0) ? 16 : 4;
        const float post = (mode == 0) ? 0.18033688f : 1.0f;   // fold softmax scale into q
#pragma unroll
        for (int mi = 0; mi < 2; ++mi) {
#pragma unroll
            for (int r = 0; r < 4; ++r) {
                int row = row0 + wr + mi * 16 + quad * 4 + r;
                int b = row >> 11, t = row & 2047;
                float c0 = ldT(cosraw, t * 32 + l15, isf32);
                float c1 = ldT(cosraw, t * 32 + 16 + l15, isf32);
                float s0 = ldT(sinraw, t * 32 + l15, isf32);
                float s1 = ldT(sinraw, t * 32 + 16 + l15, isf32);
                float v0 =  c0 * acc[mi][0][r] + s0 * acc[mi][2][r];
                float v1 =  c1 * acc[mi][1][r] + s1 * acc[mi][3][r];
                float v2 = -s0 * acc[mi][0][r] + c0 * acc[mi][2][r];
                float v3 = -s1 * acc[mi][1][r] + c1 * acc[mi][3][r];
                float ss = v0 * v0 + v1 * v1 + v2 * v2 + v3 * v3;
                ss += __shfl_xor(ss, 1); ss += __shfl_xor(ss, 2);
                ss += __shfl_xor(ss, 4); ss += __shfl_xor(ss, 8);
                float sc = rsqrtf(ss * (1.f / 64.f) + 1.1920929e-7f) * post;
                size_t base = (((size_t)b * nh + h) * 2048 + t) * 64;
                dst[base + 0 * 16 + l15] = (__bf16)(v0 * sc);
                dst[base + 1 * 16 + l15] = (__bf16)(v1 * sc);
                dst[base + 2 * 16 + l15] = (__bf16)(v2 * sc);
                dst[base + 3 * 16 + l15] = (__bf16)(v3 * sc);
            }
        }
    } else {
        // vT[(b*4+h)*64 + d][t], packed 4 consecutive t per store
#pragma unroll
        for (int mi = 0; mi < 2; ++mi) {
            int rowb = row0 + wr + mi * 16 + quad * 4;
            int b = rowb >> 11, t0 = rowb & 2047;
            float gg[4];
#pragma unroll
            for (int r = 0; r < 4; ++r) {
                float zv = __shfl(zacc[mi][r], quad * 16 + h);
                gg[r] = 2.f / (1.f + __expf(-zv));
            }
#pragma unroll
            for (int nj = 0; nj < 4; ++nj) {
                int d = nj * 16 + l15;
                bf16x4 pack;
#pragma unroll
                for (int r = 0; r < 4; ++r) {
                    int row = rowb + r;
                    float vev = ldT(veraw, (size_t)row * 256 + h * 64 + d, isf32);
                    pack[r] = (__bf16)(acc[mi][nj][r] + gg[r] * vev);
                }
                size_t a = (((size_t)b * 4 + h) * 64 + d) * 2048 + t0;
                *(bf16x4*)(&vTo[a]) = pack;
            }
        }
    }
}

// ---------------------------------------------------------------------------
// Kernel 3: sliding-window causal GQA flash attention, transposed-score form.
// Block = 64 q-rows x 2 heads sharing the same kv-head (GQA): waves 0-1 run
// head A, waves 2-3 head B, each wave 32 q-rows. K/V staged ONCE per tile
// serves both heads; 64-row span needs ~17 tiles vs 18 for 128 (-5.5% work).
// Mask split into causal-only / window-only wave-uniform predicates.
// Grid (32, 8, 2).
// ---------------------------------------------------------------------------
__global__ __launch_bounds__(256) void attn_kernel(
    const __bf16* __restrict__ qg, const __bf16* __restrict__ kg,
    const __bf16* __restrict__ vTg, __bf16* __restrict__ yo,
    const int* __restrict__ winp)
{
    const int b = blockIdx.z;
    const int qb = b ? (31 - blockIdx.x) : blockIdx.x;   // heavy+light pairing
    const int q0 = qb * 64;
    const int hp = blockIdx.y;              // head pair: heads 2hp, 2hp+1
    const int kvh = hp >> 1;
    const int W = winp[0];

    const int tid  = threadIdx.x;
    const int w    = tid >> 6;
    const int lane = tid & 63;
    const int quad = lane >> 4;
    const int l15  = lane & 15;
    const int hh   = hp * 2 + (w >> 1);     // this wave's head
    const int wq   = (w & 1) * 32;          // this wave's q-offset in block

    __shared__ __align__(16) __bf16 Ks[2][64 * 64];   // [t][d], XOR-swizzled
    __shared__ __align__(16) __bf16 Vt[2][64 * 64];   // [d][t], XOR-swizzled
    __shared__ __align__(16) __bf16 Ps[4][32 * 64];   // per-wave P[q][t], swizzled

    bf16x8 qf[2][2];   // B-frag: lane n = q-row, regs k = d
#pragma unroll
    for (int i = 0; i < 2; ++i) {
        size_t qb_ = (((size_t)b * 16 + hh) * 2048 + q0 + wq + i * 16 + l15) * 64;
        qf[i][0] = *(const bf16x8*)(&qg[qb_ + quad * 8]);
        qf[i][1] = *(const bf16x8*)(&qg[qb_ + 32 + quad * 8]);
    }

    f32x4 oacc[2][4];   // O^T: lane = q-row, [dg] d-groups, regs = d in group
    float lsum[2] = {0.f, 0.f};
#pragma unroll
    for (int i = 0; i < 2; ++i)
#pragma unroll
        for (int dg = 0; dg < 4; ++dg) oacc[i][dg] = (f32x4){0.f, 0.f, 0.f, 0.f};

    const int lo = q0 - W;
    const int kt_lo = lo > 0 ? (lo >> 6) : 0;
    const int kt_hi = q0 >> 6;
    const size_t kvbase = ((size_t)b * 4 + kvh) * 2048 * 64;

    auto stage = [&](int buf, int k0) {
#pragma unroll
        for (int i = 0; i < 2; ++i) {
            int c = i * 256 + tid;
            int rr = c >> 3;
            int jj = (c & 7) ^ (rr & 7);
            cp16(&Ks[buf][c * 8], &kg[kvbase + (size_t)(k0 + rr) * 64 + jj * 8]);
            cp16(&Vt[buf][c * 8], &vTg[kvbase + (size_t)rr * 2048 + k0 + jj * 8]);
        }
    };

    stage(0, kt_lo * 64);
    __syncthreads();

    int cur = 0;
    for (int kt = kt_lo; kt <= kt_hi; ++kt) {
        const int k0 = kt * 64;
        const bool need_c = (k0 + 63 > q0);           // causal: diagonal tile only
        const bool need_w = (q0 + 63 - k0 > W);       // window: trailing tiles only
        if (kt < kt_hi) stage(cur ^ 1, k0 + 64);      // async prefetch

        // QK^T transposed: sacc[i][g] = S^T, row = t_local g*16+quad*4+r, col = q
        f32x4 sacc[2][4];
#pragma unroll
        for (int i = 0; i < 2; ++i)
#pragma unroll
            for (int g = 0; g < 4; ++g) sacc[i][g] = (f32x4){0.f, 0.f, 0.f, 0.f};
        const __bf16* Kc = &Ks[cur][0];
#pragma unroll
        for (int g = 0; g < 4; ++g) {
            int t = g * 16 + l15;
            bf16x8 kf0 = *(const bf16x8*)(&Kc[t * 64 + (quad ^ (t & 7)) * 8]);
            bf16x8 kf1 = *(const bf16x8*)(&Kc[t * 64 + ((4 + quad) ^ (t & 7)) * 8]);
#pragma unroll
            for (int i = 0; i < 2; ++i) {
                sacc[i][g] = __builtin_amdgcn_mfma_f32_16x16x32_bf16(kf0, qf[i][0], sacc[i][g], 0, 0, 0);
                sacc[i][g] = __builtin_amdgcn_mfma_f32_16x16x32_bf16(kf1, qf[i][1], sacc[i][g], 0, 0, 0);
            }
        }

        // softmax (p = exp2(s), q pre-scaled); packed b64 stores into Ps[q][t]
#pragma unroll
        for (int i = 0; i < 2; ++i) {
            const int qrow = q0 + wq + i * 16 + l15;
#pragma unroll
            for (int g = 0; g < 4; ++g) {
                bf16x4 pk;
#pragma unroll
                for (int r = 0; r < 4; ++r) {
                    float p = exp2f(sacc[i][g][r]);
                    if (need_c || need_w) {
                        int col = k0 + g * 16 + quad * 4 + r;
                        bool ok = true;
                        if (need_c) ok = (col <= qrow);
                        if (need_w) ok = ok && (qrow - col <= W);
                        p = ok ? p : 0.f;
                    }
                    lsum[i] += p;
                    pk[r] = (__bf16)p;
                }
                int ch = ((g * 2 + (quad >> 1)) ^ (l15 & 7)) * 8 + (quad & 1) * 4;
                *(bf16x4*)(&Ps[w][(i * 16 + l15) * 64 + ch]) = pk;
            }
        }
        asm volatile("s_waitcnt lgkmcnt(0)" ::: "memory");   // wave-local Ps ordering

        // PV: O^T = Vt(A) x P(B); Vt-frags shared across both q-groups
        const __bf16* Vc = &Vt[cur][0];
#pragma unroll
        for (int ks = 0; ks < 2; ++ks) {
            bf16x8 pB[2];
#pragma unroll
            for (int i = 0; i < 2; ++i)
                pB[i] = *(const bf16x8*)(&Ps[w][(i * 16 + l15) * 64 + ((ks * 4 + quad) ^ (l15 & 7)) * 8]);
#pragma unroll
            for (int dg = 0; dg < 4; ++dg) {
                int m = dg * 16 + l15;
                bf16x8 av = *(const bf16x8*)(&Vc[m * 64 + ((ks * 4 + quad) ^ (m & 7)) * 8]);
                oacc[0][dg] = __builtin_amdgcn_mfma_f32_16x16x32_bf16(av, pB[0], oacc[0][dg], 0, 0, 0);
                oacc[1][dg] = __builtin_amdgcn_mfma_f32_16x16x32_bf16(av, pB[1], oacc[1][dg], 0, 0, 0);
            }
        }

        __syncthreads();   // drains prefetch cp16 + protects buffers
        cur ^= 1;
    }

#pragma unroll
    for (int i = 0; i < 2; ++i) {
        float l = lsum[i];
        l += __shfl_xor(l, 16); l += __shfl_xor(l, 32);   // sum over quads (same q)
        float inv = 1.f / l;
        int q = q0 + wq + i * 16 + l15;
        size_t base = ((size_t)(b * 2048 + q)) * 1024 + hh * 64;
#pragma unroll
        for (int dg = 0; dg < 4; ++dg) {
            bf16x4 ov;
#pragma unroll
            for (int r = 0; r < 4; ++r) ov[r] = (__bf16)(oacc[i][dg][r] * inv);
            *(bf16x4*)(&yo[base + dg * 16 + quad * 4]) = ov;
        }
    }
}

// ---------------------------------------------------------------------------
// Kernel 4: output projection, 128x64 tiles, BK=64 double-buffered.
// Output dtype via self-sniff of x. Grid: (32, 16).
// ---------------------------------------------------------------------------
__global__ __launch_bounds__(256) void proj_kernel(
    const __bf16* __restrict__ y, const __bf16* __restrict__ WpT,
    void* __restrict__ outp, const void* __restrict__ xraw)
{
    const int isf32 = sniff_block(xraw);
    const int row0 = blockIdx.x * 128;
    const int col0 = blockIdx.y * 64;
    __shared__ __align__(16) __bf16 As[2][128 * 64];
    __shared__ __align__(16) __bf16 Bs[2][64 * 64];

    const int tid  = threadIdx.x;
    const int w    = tid >> 6;
    const int lane = tid & 63;
    const int quad = lane >> 4;
    const int l15  = lane & 15;
    const int wr   = w * 32;

    f32x4 acc[2][4];
#pragma unroll
    for (int mi = 0; mi < 2; ++mi)
#pragma unroll
        for (int nj = 0; nj < 4; ++nj) acc[mi][nj] = (f32x4){0.f, 0.f, 0.f, 0.f};

    auto stage = [&](int buf, int kk) {
#pragma unroll
        for (int i = 0; i < 4; ++i) {
            int c = i * 256 + tid;
            cp16(&As[buf][c * 8], &y[(size_t)(row0 + (c >> 3)) * 1024 + kk + ((c & 7) << 3)]);
        }
#pragma unroll
        for (int i = 0; i < 2; ++i) {
            int c = i * 256 + tid;
            cp16(&Bs[buf][c * 8], &WpT[(size_t)(col0 + (c >> 3)) * 1024 + kk + ((c & 7) << 3)]);
        }
    };

    stage(0, 0);
    __syncthreads();

    for (int kk = 0; kk < 1024; kk += 64) {
        const int cur = (kk >> 6) & 1;
        if (kk + 64 < 1024) stage(cur ^ 1, kk + 64);

        bf16x8 a[2][2], bfr[4][2];
#pragma unroll
        for (int mi = 0; mi < 2; ++mi)
#pragma unroll
            for (int kh = 0; kh < 2; ++kh)
                a[mi][kh] = *(const bf16x8*)(&As[cur][(wr + mi * 16 + l15) * 64 + kh * 32 + quad * 8]);
#pragma unroll
        for (int nj = 0; nj < 4; ++nj)
#pragma unroll
            for (int kh = 0; kh < 2; ++kh)
                bfr[nj][kh] = *(const bf16x8*)(&Bs[cur][(nj * 16 + l15) * 64 + kh * 32 + quad * 8]);
#pragma unroll
        for (int kh = 0; kh < 2; ++kh)
#pragma unroll
            for (int mi = 0; mi < 2; ++mi)
#pragma unroll
                for (int nj = 0; nj < 4; ++nj)
                    acc[mi][nj] = __builtin_amdgcn_mfma_f32_16x16x32_bf16(a[mi][kh], bfr[nj][kh], acc[mi][nj], 0, 0, 0);
        __syncthreads();
    }

#pragma unroll
    for (int mi = 0; mi < 2; ++mi)
#pragma unroll
        for (int r = 0; r < 4; ++r) {
            int row = row0 + wr + mi * 16 + quad * 4 + r;
            if (isf32) {
                float* out = (float*)outp;
#pragma unroll
                for (int nj = 0; nj < 4; ++nj)
                    out[(size_t)row * 1024 + col0 + nj * 16 + l15] = acc[mi][nj][r];
            } else {
                __bf16* out = (__bf16*)outp;
#pragma unroll
                for (int nj = 0; nj < 4; ++nj)
                    out[(size_t)row * 1024 + col0 + nj * 16 + l15] = (__bf16)acc[mi][nj][r];
            }
        }
}

extern "C" void kernel_launch(void* const* d_in, const int* in_sizes, int n_in,
                              void* d_out, int out_size, void* d_ws, size_t ws_size,
                              hipStream_t stream) {
    const int* win = (const int*)d_in[9];

    char* p = (char*)d_ws;
    __bf16* q_ws = (__bf16*)p;                 p += (size_t)4194304 * 2;
    __bf16* k_ws = (__bf16*)p;                 p += (size_t)1048576 * 2;
    __bf16* vT_ws= (__bf16*)p;                 p += (size_t)1048576 * 2;
    __bf16* y_ws = (__bf16*)p;                 p += (size_t)4194304 * 2;
    __bf16* xb   = (__bf16*)p;                 p += (size_t)4194304 * 2;
    __bf16* WqT  = (__bf16*)p;                 p += (size_t)1048576 * 2;
    __bf16* WkT  = (__bf16*)p;                 p += (size_t)262144 * 2;
    __bf16* WvT  = (__bf16*)p;                 p += (size_t)262144 * 2;
    __bf16* WpT  = (__bf16*)p;                 p += (size_t)1048576 * 2;
    __bf16* wgb  = (__bf16*)p;                 p += 256;

    prep_kernel<<<2689, 256, 0, stream>>>(
        d_in[0], d_in[4], d_in[5], d_in[6], d_in[7], d_in[8],
        xb, WqT, WkT, WvT, WpT, wgb);

    qkv_kernel<<<dim3(32, 24), 256, 0, stream>>>(
        xb, d_in[0], d_in[1], d_in[2], d_in[3],
        WqT, WkT, WvT, wgb, q_ws, k_ws, vT_ws);

    attn_kernel<<<dim3(32, 8, 2), 256, 0, stream>>>(q_ws, k_ws, vT_ws, y_ws, win);

    proj_kernel<<<dim3(32, 16), 256, 0, stream>>>(y_ws, WpT, d_out, d_in[0]);
}